// Round 10
// baseline (368.961 us; speedup 1.0000x reference)
//
#include <hip/hip_runtime.h>

#define DEVI __device__ __forceinline__

typedef __attribute__((ext_vector_type(8))) __bf16 bf16x8;
typedef __attribute__((ext_vector_type(4))) float f32x4;
typedef __attribute__((ext_vector_type(16))) float f32x16;
typedef __attribute__((ext_vector_type(4))) unsigned uint32x4;

DEVI __bf16 f2bf(float f) {
  unsigned u = __builtin_bit_cast(unsigned, f);
  unsigned r = u + 0x7fffu + ((u >> 16) & 1u);
  unsigned short h = (unsigned short)(r >> 16);
  return __builtin_bit_cast(__bf16, h);
}

DEVI unsigned cvt_pk_bf16(float lo, float hi) {
  unsigned r;
  asm("v_cvt_pk_bf16_f32 %0, %1, %2" : "=v"(r) : "v"(lo), "v"(hi));
  return r;
}

DEVI void load_lds16(const void* g, void* l) {
  __builtin_amdgcn_global_load_lds((__attribute__((address_space(1))) const void*)g,
                                   (__attribute__((address_space(3))) void*)l,
                                   16, 0, 0);
}

// all four 1024x1024 weight matrices in one launch
__global__ void convert_w4(const float* __restrict__ w0, const float* __restrict__ w1,
                           const float* __restrict__ w2, const float* __restrict__ w3,
                           __bf16* __restrict__ o0, __bf16* __restrict__ o1,
                           __bf16* __restrict__ o2, __bf16* __restrict__ o3, int n8) {
  int stride = gridDim.x * blockDim.x;
  for (int i = blockIdx.x * blockDim.x + threadIdx.x; i < 4 * n8; i += stride) {
    int sel = i / n8, j = i - sel * n8;
    const float* in = sel == 0 ? w0 : sel == 1 ? w1 : sel == 2 ? w2 : w3;
    __bf16* out = sel == 0 ? o0 : sel == 1 ? o1 : sel == 2 ? o2 : o3;
    float4 a = ((const float4*)in)[j * 2];
    float4 b = ((const float4*)in)[j * 2 + 1];
    bf16x8 o;
    o[0] = f2bf(a.x); o[1] = f2bf(a.y); o[2] = f2bf(a.z); o[3] = f2bf(a.w);
    o[4] = f2bf(b.x); o[5] = f2bf(b.y); o[6] = f2bf(b.z); o[7] = f2bf(b.w);
    ((bf16x8*)out)[j] = o;
  }
}

// ---------------------------------------------------------------------------
// FUSED QKV projection GEMM, depth-2 counted pipeline (round-9, unchanged).
// ---------------------------------------------------------------------------
__global__ __launch_bounds__(256, 3) void gemm_qkv(
    const float* __restrict__ qa, const float* __restrict__ ka, const float* __restrict__ va,
    const __bf16* __restrict__ Wq, const __bf16* __restrict__ Wk, const __bf16* __restrict__ Wv,
    const float* __restrict__ bq, const float* __restrict__ bk, const float* __restrict__ bv,
    __bf16* __restrict__ Qh, __bf16* __restrict__ Kh, __bf16* __restrict__ Vt)
{
  __shared__ __align__(16) __bf16 As[3][128 * 32];
  __shared__ __align__(16) __bf16 Bs[3][128 * 32];
  const int sel = blockIdx.z;
  const float* A = sel == 0 ? qa : sel == 1 ? ka : va;
  const __bf16* W = sel == 0 ? Wq : sel == 1 ? Wk : Wv;
  const float* bias = sel == 0 ? bq : sel == 1 ? bk : bv;
  __bf16* outp = sel == 0 ? Qh : sel == 1 ? Kh : Vt;
  const bool vmode = (sel == 2);

  const int tid = threadIdx.x;
  const int lane = tid & 63;
  const int ln = lane & 15, g = lane >> 4;
  const int w = tid >> 6;
  const int wr = w >> 1, wc = w & 1;
  const int id = blockIdx.y * 64 + blockIdx.x;
  const int bx = 8 * (id & 7) + ((id >> 3) & 7);
  const int by = id >> 6;
  const int row0 = bx * 128, col0 = by * 128;

  const int ar = tid >> 1, ah = tid & 1;
  const int axr = (ar >> 1) & 3;

  f32x4 acc[4][4] = {};
  float4 fa0[4], fa1[4];

  auto issueA = [&](int kt, float4* f) {
    const float4* src = (const float4*)&A[(size_t)(row0 + ar) * 1024 + kt * 32 + ah * 16];
#pragma unroll
    for (int j = 0; j < 4; ++j) f[j] = src[j];
  };
  auto issueW = [&](int buf, int kt) {
#pragma unroll
    for (int i = 0; i < 2; ++i) {
      int c = tid + 256 * i;
      int r = c >> 2, sl = c & 3;
      int so = 8 * (sl ^ ((r >> 1) & 3));
      load_lds16(&W[(size_t)(col0 + r) * 1024 + kt * 32 + so], &Bs[buf][c * 8]);
    }
  };
  auto writeA = [&](int buf, const float4* f) {
#pragma unroll
    for (int j = 0; j < 2; ++j) {
      uint32x4 o;
      o[0] = cvt_pk_bf16(f[2 * j].x, f[2 * j].y);
      o[1] = cvt_pk_bf16(f[2 * j].z, f[2 * j].w);
      o[2] = cvt_pk_bf16(f[2 * j + 1].x, f[2 * j + 1].y);
      o[3] = cvt_pk_bf16(f[2 * j + 1].z, f[2 * j + 1].w);
      int s = 2 * ah + j;
      *(uint32x4*)&As[buf][ar * 32 + (s ^ axr) * 8] = o;
    }
  };
  auto compute = [&](int buf) {
    const __bf16* as = As[buf];
    const __bf16* bs = Bs[buf];
    bf16x8 aF[4], bF[4];
#pragma unroll
    for (int mi = 0; mi < 4; ++mi) {
      int r = wr * 64 + mi * 16 + ln;
      aF[mi] = *(const bf16x8*)&as[r * 32 + ((g * 8) ^ (((r >> 1) & 3) * 8))];
    }
#pragma unroll
    for (int ni = 0; ni < 4; ++ni) {
      int r = wc * 64 + ni * 16 + ln;
      bF[ni] = *(const bf16x8*)&bs[r * 32 + ((g * 8) ^ (((r >> 1) & 3) * 8))];
    }
    __builtin_amdgcn_s_setprio(1);
#pragma unroll
    for (int mi = 0; mi < 4; ++mi)
#pragma unroll
      for (int ni = 0; ni < 4; ++ni)
        acc[mi][ni] = __builtin_amdgcn_mfma_f32_16x16x32_bf16(aF[mi], bF[ni], acc[mi][ni], 0, 0, 0);
    __builtin_amdgcn_s_setprio(0);
  };

#define QKV_BAR(N) \
  asm volatile("s_waitcnt vmcnt(" #N ") lgkmcnt(0)" ::: "memory"); \
  __builtin_amdgcn_s_barrier(); \
  asm volatile("" ::: "memory");

#define QKV_STEP(KT, E, FAC, FAN) \
  QKV_BAR(6) \
  issueA((KT) + 2, FAC); \
  issueW(((E) + 2) % 3, (KT) + 2); \
  compute((E) % 3); \
  writeA(((E) + 1) % 3, FAN);

  issueA(0, fa0); issueW(0, 0);
  issueA(1, fa1); issueW(1, 1);
  writeA(0, fa0);

#pragma unroll 1
  for (int u = 0; u < 5; ++u) {
    const int kt = 6 * u;
    QKV_STEP(kt + 0, 0, fa0, fa1)
    QKV_STEP(kt + 1, 1, fa1, fa0)
    QKV_STEP(kt + 2, 2, fa0, fa1)
    QKV_STEP(kt + 3, 3, fa1, fa0)
    QKV_STEP(kt + 4, 4, fa0, fa1)
    QKV_STEP(kt + 5, 5, fa1, fa0)
  }
  QKV_BAR(6)
  compute(0);
  asm volatile("s_waitcnt vmcnt(2)" ::: "memory");
  writeA(1, fa1);
  QKV_BAR(0)
  compute(1);
#undef QKV_STEP
#undef QKV_BAR

#pragma unroll
  for (int ni = 0; ni < 4; ++ni) {
    int n = col0 + wc * 64 + ni * 16 + ln;
    float bv = bias[n];
#pragma unroll
    for (int mi = 0; mi < 4; ++mi) {
#pragma unroll
      for (int i = 0; i < 4; ++i) {
        int m = row0 + wr * 64 + mi * 16 + g * 4 + i;
        float val = acc[mi][ni][i] + bv;
        int b = m >> 11, s = m & 2047, h = n >> 6, d = n & 63;
        size_t idx = vmode
          ? ((size_t)((b * 16 + h) * 64 + d) * 2048 + s)
          : ((size_t)((b * 16 + h) * 2048 + s) * 64 + d);
        outp[idx] = f2bf(val);
      }
    }
  }
}

// ---------------------------------------------------------------------------
// Output GEMM (bf16 A = Ctx): depth-2 counted-vmcnt, MODE 2 (fp32 out).
// ---------------------------------------------------------------------------
template<int MODE>
__global__ __launch_bounds__(256, 2) void gemm_bt(
    const __bf16* __restrict__ A, const __bf16* __restrict__ W,
    const float* __restrict__ bias, void* __restrict__ outp)
{
  __shared__ __bf16 As[3][128 * 32];
  __shared__ __bf16 Bs[3][128 * 32];
  const int tid = threadIdx.x;
  const int lane = tid & 63;
  const int ln = lane & 15, g = lane >> 4;
  const int w = tid >> 6;
  const int wr = w >> 1, wc = w & 1;
  const int id = blockIdx.y * 64 + blockIdx.x;
  const int bx = 8 * (id & 7) + ((id >> 3) & 7);
  const int by = id >> 6;
  const int row0 = bx * 128, col0 = by * 128;

  f32x4 acc[4][4] = {};

  auto stage = [&](int buf, int kt) {
    const int k0 = kt * 32;
#pragma unroll
    for (int i = 0; i < 2; ++i) {
      int c = tid + 256 * i;
      int r = c >> 2, sl = c & 3;
      int so = 8 * (sl ^ ((r >> 1) & 3));
      load_lds16(&A[(size_t)(row0 + r) * 1024 + k0 + so], &As[buf][c * 8]);
      load_lds16(&W[(size_t)(col0 + r) * 1024 + k0 + so], &Bs[buf][c * 8]);
    }
  };

  auto compute = [&](int buf) {
    const __bf16* as = As[buf];
    const __bf16* bs = Bs[buf];
    bf16x8 aF[4], bF[4];
#pragma unroll
    for (int mi = 0; mi < 4; ++mi) {
      int r = wr * 64 + mi * 16 + ln;
      aF[mi] = *(const bf16x8*)&as[r * 32 + ((g * 8) ^ (((r >> 1) & 3) * 8))];
    }
#pragma unroll
    for (int ni = 0; ni < 4; ++ni) {
      int r = wc * 64 + ni * 16 + ln;
      bF[ni] = *(const bf16x8*)&bs[r * 32 + ((g * 8) ^ (((r >> 1) & 3) * 8))];
    }
    __builtin_amdgcn_s_setprio(1);
#pragma unroll
    for (int mi = 0; mi < 4; ++mi)
#pragma unroll
      for (int ni = 0; ni < 4; ++ni)
        acc[mi][ni] = __builtin_amdgcn_mfma_f32_16x16x32_bf16(aF[mi], bF[ni], acc[mi][ni], 0, 0, 0);
    __builtin_amdgcn_s_setprio(0);
  };

  stage(0, 0);
  stage(1, 1);
#pragma unroll 1
  for (int kt = 0; kt < 31; ++kt) {
    asm volatile("s_waitcnt vmcnt(4)" ::: "memory");
    __builtin_amdgcn_s_barrier();
    asm volatile("" ::: "memory");
    if (kt + 2 < 32) stage((kt + 2) % 3, kt + 2);
    compute(kt % 3);
  }
  asm volatile("s_waitcnt vmcnt(0)" ::: "memory");
  __builtin_amdgcn_s_barrier();
  asm volatile("" ::: "memory");
  compute(31 % 3);

#pragma unroll
  for (int ni = 0; ni < 4; ++ni) {
    int n = col0 + wc * 64 + ni * 16 + ln;
    float bv = bias[n];
#pragma unroll
    for (int mi = 0; mi < 4; ++mi) {
#pragma unroll
      for (int i = 0; i < 4; ++i) {
        int m = row0 + wr * 64 + mi * 16 + g * 4 + i;
        float val = acc[mi][ni][i] + bv;
        if (MODE == 2) {
          ((float*)outp)[(size_t)m * 1024 + n] = val;
        } else {
          int b = m >> 11, s = m & 2047, h = n >> 6, d = n & 63;
          size_t idx = (MODE == 0)
            ? ((size_t)((b * 16 + h) * 2048 + s) * 64 + d)
            : ((size_t)((b * 16 + h) * 64 + d) * 2048 + s);
          ((__bf16*)outp)[idx] = f2bf(val);
        }
      }
    }
  }
}

// ---------------------------------------------------------------------------
// Causal flash attention, BARRIER-FREE: no K/V LDS staging — MFMA fragments
// read directly from global (Qh/Kh/Vt are L2/L3-resident; fragment pattern
// covers each 128B K/V row exactly once per tile, 16B-aligned dwordx4 loads).
// No split-KV, no combine, ZERO __syncthreads, ZERO LDS -> occupancy bound
// only by VGPR (6-8 waves/SIMD). 8 waves/block: waves 0-3 = strip 15-y,
// waves 4-7 = strip y (exact per-block work balance). 32x32x16 MFMA,
// swapped-operand, P in registers, FIXED-MAX softmax (p=exp2((s-40)*CE)).
// ---------------------------------------------------------------------------
__global__ __launch_bounds__(512, 6) void attn_fwd(
    const __bf16* __restrict__ Qh, const __bf16* __restrict__ Kh,
    const __bf16* __restrict__ Vt, __bf16* __restrict__ Ctx)
{
  const int tid = threadIdx.x;
  const int lane = tid & 63;
  const int l31 = lane & 31, hl = lane >> 5;
  const int w = tid >> 6;                            // 0..7
  const int wq3 = w & 3, sel = w >> 2;               // quarter, strip select
  const int bh = blockIdx.x;
  const int b = bh >> 4, h = bh & 15;
  const int y = blockIdx.y;
  const int qb = sel ? y : 15 - y;                   // waves 0-3 heavy, 4-7 light
  const float CE = 0.18033688f;                      // (1/sqrt(64)) * log2(e)
  const float MC = 40.0f * CE;                       // fixed softmax max (raw units)

  const __bf16* Kb = Kh + (size_t)bh * 2048 * 64;
  const __bf16* Vb = Vt + (size_t)bh * 64 * 2048;

  const int qw = qb * 128 + wq3 * 32;
  const int qglob = qw + l31;
  const int tlim = (qw + 31) / 64 + 1;               // tiles up to the diagonal

  // Q fragments (B-operand): B[k=d][n=q=l31], d = ds*16 + hl*8 + j
  bf16x8 qF[4];
#pragma unroll
  for (int ds = 0; ds < 4; ++ds)
    qF[ds] = *(const bf16x8*)&Qh[((size_t)bh * 2048 + qglob) * 64 + ds * 16 + hl * 8];

  f32x16 oT[2] = {};                 // O^T: d = dblk*32 + (r&3)+8*(r>>2)+4*hl, q = l31
  float lrun = 0.f;

#pragma unroll 1
  for (int tt = 0; tt < tlim; ++tt) {
    const int kv0 = tt * 64;

    // ---- S^T = K Q^T : C[m=kv][n=q=l31], kv_local = (r&3)+8*(r>>2)+4*hl ----
    f32x16 sT[2] = {};
#pragma unroll
    for (int kblk = 0; kblk < 2; ++kblk) {
      bf16x8 aK[4];
      const int r = kv0 + kblk * 32 + l31;
#pragma unroll
      for (int ds = 0; ds < 4; ++ds)
        aK[ds] = *(const bf16x8*)&Kb[(size_t)r * 64 + ds * 16 + hl * 8];
      __builtin_amdgcn_s_setprio(1);
#pragma unroll
      for (int ds = 0; ds < 4; ++ds)
        sT[kblk] = __builtin_amdgcn_mfma_f32_32x32x16_bf16(aK[ds], qF[ds], sT[kblk], 0, 0, 0);
      __builtin_amdgcn_s_setprio(0);
    }

    // ---- causal mask (diagonal tiles only) ----
    if (kv0 + 63 > qw) {
#pragma unroll
      for (int kblk = 0; kblk < 2; ++kblk)
#pragma unroll
        for (int r = 0; r < 16; ++r) {
          int kvg = kv0 + kblk * 32 + (r & 3) + 8 * (r >> 2) + 4 * hl;
          sT[kblk][r] = (kvg <= qglob) ? sT[kblk][r] : -3e38f;
        }
    }

    // ---- fixed-max exp + pack to bf16 words (in registers) ----
    unsigned c0[8], c1[8];
    float ps0 = 0.f, ps1 = 0.f, ps2 = 0.f, ps3 = 0.f;
#pragma unroll
    for (int w2 = 0; w2 < 8; ++w2) {
      float p0 = exp2f(__builtin_fmaf(sT[0][2 * w2],     CE, -MC));
      float p1 = exp2f(__builtin_fmaf(sT[0][2 * w2 + 1], CE, -MC));
      float p2 = exp2f(__builtin_fmaf(sT[1][2 * w2],     CE, -MC));
      float p3 = exp2f(__builtin_fmaf(sT[1][2 * w2 + 1], CE, -MC));
      ps0 += p0; ps1 += p1; ps2 += p2; ps3 += p3;
      c0[w2] = cvt_pk_bf16(p0, p1);
      c1[w2] = cvt_pk_bf16(p2, p3);
    }
    lrun += (ps0 + ps1) + (ps2 + ps3);

    // ---- in-register P redistribution: score layout -> B-operand frags ----
    // Wv[ks=2*kblk+ksl][a]: kv pair ksl*16 + hl*8 + 2a (+kblk*32), col q=l31.
    uint32x4 Wv[4];
#pragma unroll
    for (int kblk = 0; kblk < 2; ++kblk)
#pragma unroll
      for (int ksl = 0; ksl < 2; ++ksl)
#pragma unroll
        for (int al = 0; al < 2; ++al) {
          unsigned cp = kblk ? c1[4 * ksl + al]     : c0[4 * ksl + al];
          unsigned cq = kblk ? c1[4 * ksl + 2 + al] : c0[4 * ksl + 2 + al];
          unsigned cqx = __shfl_xor(cq, 32);
          unsigned cpx = __shfl_xor(cp, 32);
          Wv[kblk * 2 + ksl][al]     = hl ? cqx : cp;
          Wv[kblk * 2 + ksl][al + 2] = hl ? cq  : cpx;
        }

    // ---- O^T += V^T P^T : A = Vt rows (m=d), B = P frags (n=q=l31) ----
#pragma unroll
    for (int dblk = 0; dblk < 2; ++dblk) {
      bf16x8 aV[4];
      const int rv = dblk * 32 + l31;
#pragma unroll
      for (int ks = 0; ks < 4; ++ks)
        aV[ks] = *(const bf16x8*)&Vb[(size_t)rv * 2048 + kv0 + ks * 16 + hl * 8];
      __builtin_amdgcn_s_setprio(1);
#pragma unroll
      for (int ks = 0; ks < 4; ++ks)
        oT[dblk] = __builtin_amdgcn_mfma_f32_32x32x16_bf16(
            aV[ks], __builtin_bit_cast(bf16x8, Wv[ks]), oT[dblk], 0, 0, 0);
      __builtin_amdgcn_s_setprio(0);
    }
  }

  // ---- finalize: l cross-half add (q=l31 in-lane), write ctx [B][S][1024] ----
  lrun += __shfl_xor(lrun, 32);
  const float inv = 1.0f / fmaxf(lrun, 1e-30f);
#pragma unroll
  for (int dblk = 0; dblk < 2; ++dblk)
#pragma unroll
    for (int rb = 0; rb < 4; ++rb) {
      unsigned u0 = cvt_pk_bf16(oT[dblk][4 * rb]     * inv, oT[dblk][4 * rb + 1] * inv);
      unsigned u1 = cvt_pk_bf16(oT[dblk][4 * rb + 2] * inv, oT[dblk][4 * rb + 3] * inv);
      int d = dblk * 32 + rb * 8 + 4 * hl;
      size_t idx = ((size_t)(b * 2048 + qglob)) * 1024 + h * 64 + d;
      *(uint2*)&Ctx[idx] = make_uint2(u0, u1);
    }
}

// ---------------------------------------------------------------------------
extern "C" void kernel_launch(void* const* d_in, const int* in_sizes, int n_in,
                              void* d_out, int out_size, void* d_ws, size_t ws_size,
                              hipStream_t stream) {
  const float* q  = (const float*)d_in[0];
  const float* k  = (const float*)d_in[1];
  const float* v  = (const float*)d_in[2];
  const float* wq = (const float*)d_in[3];
  const float* bq = (const float*)d_in[4];
  const float* wk = (const float*)d_in[5];
  const float* bk = (const float*)d_in[6];
  const float* wv = (const float*)d_in[7];
  const float* bv = (const float*)d_in[8];
  const float* wo = (const float*)d_in[9];
  const float* bo = (const float*)d_in[10];
  float* out = (float*)d_out;
  char* ws = (char*)d_ws;

  const size_t MB = 1024 * 1024;
  __bf16* Wqb  = (__bf16*)(ws + 0 * MB);
  __bf16* Wkb  = (__bf16*)(ws + 2 * MB);
  __bf16* Wvb  = (__bf16*)(ws + 4 * MB);
  __bf16* Wob  = (__bf16*)(ws + 6 * MB);
  __bf16* Ctx  = (__bf16*)(ws + 8 * MB);   // 16 MB
  __bf16* Qh   = (__bf16*)(ws + 24 * MB);
  __bf16* Kh   = (__bf16*)(ws + 40 * MB);
  __bf16* Vt   = (__bf16*)(ws + 56 * MB);  // ends at 72 MB

  const int W8 = 1024 * 1024 / 8;

  convert_w4<<<2048, 256, 0, stream>>>(wq, wk, wv, wo, Wqb, Wkb, Wvb, Wob, W8);

  gemm_qkv<<<dim3(64, 8, 3), 256, 0, stream>>>(q, k, v, Wqb, Wkb, Wvb,
                                               bq, bk, bv, Qh, Kh, Vt);

  attn_fwd<<<dim3(64, 8), 512, 0, stream>>>(Qh, Kh, Vt, Ctx);

  gemm_bt<2><<<dim3(64, 8), 256, 0, stream>>>(Ctx, Wob, bo, out);
}

// Round 11
// 219.006 us; speedup vs baseline: 1.6847x; 1.6847x over previous
//
#include <hip/hip_runtime.h>

#define DEVI __device__ __forceinline__

typedef __attribute__((ext_vector_type(8))) __bf16 bf16x8;
typedef __attribute__((ext_vector_type(4))) float f32x4;
typedef __attribute__((ext_vector_type(16))) float f32x16;
typedef __attribute__((ext_vector_type(4))) unsigned uint32x4;

DEVI __bf16 f2bf(float f) {
  unsigned u = __builtin_bit_cast(unsigned, f);
  unsigned r = u + 0x7fffu + ((u >> 16) & 1u);
  unsigned short h = (unsigned short)(r >> 16);
  return __builtin_bit_cast(__bf16, h);
}

DEVI unsigned cvt_pk_bf16(float lo, float hi) {
  unsigned r;
  asm("v_cvt_pk_bf16_f32 %0, %1, %2" : "=v"(r) : "v"(lo), "v"(hi));
  return r;
}

DEVI void load_lds16(const void* g, void* l) {
  __builtin_amdgcn_global_load_lds((__attribute__((address_space(1))) const void*)g,
                                   (__attribute__((address_space(3))) void*)l,
                                   16, 0, 0);
}

// all four 1024x1024 weight matrices in one launch
__global__ void convert_w4(const float* __restrict__ w0, const float* __restrict__ w1,
                           const float* __restrict__ w2, const float* __restrict__ w3,
                           __bf16* __restrict__ o0, __bf16* __restrict__ o1,
                           __bf16* __restrict__ o2, __bf16* __restrict__ o3, int n8) {
  int stride = gridDim.x * blockDim.x;
  for (int i = blockIdx.x * blockDim.x + threadIdx.x; i < 4 * n8; i += stride) {
    int sel = i / n8, j = i - sel * n8;
    const float* in = sel == 0 ? w0 : sel == 1 ? w1 : sel == 2 ? w2 : w3;
    __bf16* out = sel == 0 ? o0 : sel == 1 ? o1 : sel == 2 ? o2 : o3;
    float4 a = ((const float4*)in)[j * 2];
    float4 b = ((const float4*)in)[j * 2 + 1];
    bf16x8 o;
    o[0] = f2bf(a.x); o[1] = f2bf(a.y); o[2] = f2bf(a.z); o[3] = f2bf(a.w);
    o[4] = f2bf(b.x); o[5] = f2bf(b.y); o[6] = f2bf(b.z); o[7] = f2bf(b.w);
    ((bf16x8*)out)[j] = o;
  }
}

// ---------------------------------------------------------------------------
// FUSED QKV projection GEMM, depth-2 counted pipeline (round-9, unchanged).
// ---------------------------------------------------------------------------
__global__ __launch_bounds__(256, 3) void gemm_qkv(
    const float* __restrict__ qa, const float* __restrict__ ka, const float* __restrict__ va,
    const __bf16* __restrict__ Wq, const __bf16* __restrict__ Wk, const __bf16* __restrict__ Wv,
    const float* __restrict__ bq, const float* __restrict__ bk, const float* __restrict__ bv,
    __bf16* __restrict__ Qh, __bf16* __restrict__ Kh, __bf16* __restrict__ Vt)
{
  __shared__ __align__(16) __bf16 As[3][128 * 32];
  __shared__ __align__(16) __bf16 Bs[3][128 * 32];
  const int sel = blockIdx.z;
  const float* A = sel == 0 ? qa : sel == 1 ? ka : va;
  const __bf16* W = sel == 0 ? Wq : sel == 1 ? Wk : Wv;
  const float* bias = sel == 0 ? bq : sel == 1 ? bk : bv;
  __bf16* outp = sel == 0 ? Qh : sel == 1 ? Kh : Vt;
  const bool vmode = (sel == 2);

  const int tid = threadIdx.x;
  const int lane = tid & 63;
  const int ln = lane & 15, g = lane >> 4;
  const int w = tid >> 6;
  const int wr = w >> 1, wc = w & 1;
  const int id = blockIdx.y * 64 + blockIdx.x;
  const int bx = 8 * (id & 7) + ((id >> 3) & 7);
  const int by = id >> 6;
  const int row0 = bx * 128, col0 = by * 128;

  const int ar = tid >> 1, ah = tid & 1;
  const int axr = (ar >> 1) & 3;

  f32x4 acc[4][4] = {};
  float4 fa0[4], fa1[4];

  auto issueA = [&](int kt, float4* f) {
    const float4* src = (const float4*)&A[(size_t)(row0 + ar) * 1024 + kt * 32 + ah * 16];
#pragma unroll
    for (int j = 0; j < 4; ++j) f[j] = src[j];
  };
  auto issueW = [&](int buf, int kt) {
#pragma unroll
    for (int i = 0; i < 2; ++i) {
      int c = tid + 256 * i;
      int r = c >> 2, sl = c & 3;
      int so = 8 * (sl ^ ((r >> 1) & 3));
      load_lds16(&W[(size_t)(col0 + r) * 1024 + kt * 32 + so], &Bs[buf][c * 8]);
    }
  };
  auto writeA = [&](int buf, const float4* f) {
#pragma unroll
    for (int j = 0; j < 2; ++j) {
      uint32x4 o;
      o[0] = cvt_pk_bf16(f[2 * j].x, f[2 * j].y);
      o[1] = cvt_pk_bf16(f[2 * j].z, f[2 * j].w);
      o[2] = cvt_pk_bf16(f[2 * j + 1].x, f[2 * j + 1].y);
      o[3] = cvt_pk_bf16(f[2 * j + 1].z, f[2 * j + 1].w);
      int s = 2 * ah + j;
      *(uint32x4*)&As[buf][ar * 32 + (s ^ axr) * 8] = o;
    }
  };
  auto compute = [&](int buf) {
    const __bf16* as = As[buf];
    const __bf16* bs = Bs[buf];
    bf16x8 aF[4], bF[4];
#pragma unroll
    for (int mi = 0; mi < 4; ++mi) {
      int r = wr * 64 + mi * 16 + ln;
      aF[mi] = *(const bf16x8*)&as[r * 32 + ((g * 8) ^ (((r >> 1) & 3) * 8))];
    }
#pragma unroll
    for (int ni = 0; ni < 4; ++ni) {
      int r = wc * 64 + ni * 16 + ln;
      bF[ni] = *(const bf16x8*)&bs[r * 32 + ((g * 8) ^ (((r >> 1) & 3) * 8))];
    }
    __builtin_amdgcn_s_setprio(1);
#pragma unroll
    for (int mi = 0; mi < 4; ++mi)
#pragma unroll
      for (int ni = 0; ni < 4; ++ni)
        acc[mi][ni] = __builtin_amdgcn_mfma_f32_16x16x32_bf16(aF[mi], bF[ni], acc[mi][ni], 0, 0, 0);
    __builtin_amdgcn_s_setprio(0);
  };

#define QKV_BAR(N) \
  asm volatile("s_waitcnt vmcnt(" #N ") lgkmcnt(0)" ::: "memory"); \
  __builtin_amdgcn_s_barrier(); \
  asm volatile("" ::: "memory");

#define QKV_STEP(KT, E, FAC, FAN) \
  QKV_BAR(6) \
  issueA((KT) + 2, FAC); \
  issueW(((E) + 2) % 3, (KT) + 2); \
  compute((E) % 3); \
  writeA(((E) + 1) % 3, FAN);

  issueA(0, fa0); issueW(0, 0);
  issueA(1, fa1); issueW(1, 1);
  writeA(0, fa0);

#pragma unroll 1
  for (int u = 0; u < 5; ++u) {
    const int kt = 6 * u;
    QKV_STEP(kt + 0, 0, fa0, fa1)
    QKV_STEP(kt + 1, 1, fa1, fa0)
    QKV_STEP(kt + 2, 2, fa0, fa1)
    QKV_STEP(kt + 3, 3, fa1, fa0)
    QKV_STEP(kt + 4, 4, fa0, fa1)
    QKV_STEP(kt + 5, 5, fa1, fa0)
  }
  QKV_BAR(6)
  compute(0);
  asm volatile("s_waitcnt vmcnt(2)" ::: "memory");
  writeA(1, fa1);
  QKV_BAR(0)
  compute(1);
#undef QKV_STEP
#undef QKV_BAR

#pragma unroll
  for (int ni = 0; ni < 4; ++ni) {
    int n = col0 + wc * 64 + ni * 16 + ln;
    float bv = bias[n];
#pragma unroll
    for (int mi = 0; mi < 4; ++mi) {
#pragma unroll
      for (int i = 0; i < 4; ++i) {
        int m = row0 + wr * 64 + mi * 16 + g * 4 + i;
        float val = acc[mi][ni][i] + bv;
        int b = m >> 11, s = m & 2047, h = n >> 6, d = n & 63;
        size_t idx = vmode
          ? ((size_t)((b * 16 + h) * 64 + d) * 2048 + s)
          : ((size_t)((b * 16 + h) * 2048 + s) * 64 + d);
        outp[idx] = f2bf(val);
      }
    }
  }
}

// ---------------------------------------------------------------------------
// Output GEMM (bf16 A = Ctx): depth-2 counted-vmcnt, MODE 2 (fp32 out).
// ---------------------------------------------------------------------------
template<int MODE>
__global__ __launch_bounds__(256, 2) void gemm_bt(
    const __bf16* __restrict__ A, const __bf16* __restrict__ W,
    const float* __restrict__ bias, void* __restrict__ outp)
{
  __shared__ __bf16 As[3][128 * 32];
  __shared__ __bf16 Bs[3][128 * 32];
  const int tid = threadIdx.x;
  const int lane = tid & 63;
  const int ln = lane & 15, g = lane >> 4;
  const int w = tid >> 6;
  const int wr = w >> 1, wc = w & 1;
  const int id = blockIdx.y * 64 + blockIdx.x;
  const int bx = 8 * (id & 7) + ((id >> 3) & 7);
  const int by = id >> 6;
  const int row0 = bx * 128, col0 = by * 128;

  f32x4 acc[4][4] = {};

  auto stage = [&](int buf, int kt) {
    const int k0 = kt * 32;
#pragma unroll
    for (int i = 0; i < 2; ++i) {
      int c = tid + 256 * i;
      int r = c >> 2, sl = c & 3;
      int so = 8 * (sl ^ ((r >> 1) & 3));
      load_lds16(&A[(size_t)(row0 + r) * 1024 + k0 + so], &As[buf][c * 8]);
      load_lds16(&W[(size_t)(col0 + r) * 1024 + k0 + so], &Bs[buf][c * 8]);
    }
  };

  auto compute = [&](int buf) {
    const __bf16* as = As[buf];
    const __bf16* bs = Bs[buf];
    bf16x8 aF[4], bF[4];
#pragma unroll
    for (int mi = 0; mi < 4; ++mi) {
      int r = wr * 64 + mi * 16 + ln;
      aF[mi] = *(const bf16x8*)&as[r * 32 + ((g * 8) ^ (((r >> 1) & 3) * 8))];
    }
#pragma unroll
    for (int ni = 0; ni < 4; ++ni) {
      int r = wc * 64 + ni * 16 + ln;
      bF[ni] = *(const bf16x8*)&bs[r * 32 + ((g * 8) ^ (((r >> 1) & 3) * 8))];
    }
    __builtin_amdgcn_s_setprio(1);
#pragma unroll
    for (int mi = 0; mi < 4; ++mi)
#pragma unroll
      for (int ni = 0; ni < 4; ++ni)
        acc[mi][ni] = __builtin_amdgcn_mfma_f32_16x16x32_bf16(aF[mi], bF[ni], acc[mi][ni], 0, 0, 0);
    __builtin_amdgcn_s_setprio(0);
  };

  stage(0, 0);
  stage(1, 1);
#pragma unroll 1
  for (int kt = 0; kt < 31; ++kt) {
    asm volatile("s_waitcnt vmcnt(4)" ::: "memory");
    __builtin_amdgcn_s_barrier();
    asm volatile("" ::: "memory");
    if (kt + 2 < 32) stage((kt + 2) % 3, kt + 2);
    compute(kt % 3);
  }
  asm volatile("s_waitcnt vmcnt(0)" ::: "memory");
  __builtin_amdgcn_s_barrier();
  asm volatile("" ::: "memory");
  compute(31 % 3);

#pragma unroll
  for (int ni = 0; ni < 4; ++ni) {
    int n = col0 + wc * 64 + ni * 16 + ln;
    float bv = bias[n];
#pragma unroll
    for (int mi = 0; mi < 4; ++mi) {
#pragma unroll
      for (int i = 0; i < 4; ++i) {
        int m = row0 + wr * 64 + mi * 16 + g * 4 + i;
        float val = acc[mi][ni][i] + bv;
        if (MODE == 2) {
          ((float*)outp)[(size_t)m * 1024 + n] = val;
        } else {
          int b = m >> 11, s = m & 2047, h = n >> 6, d = n & 63;
          size_t idx = (MODE == 0)
            ? ((size_t)((b * 16 + h) * 2048 + s) * 64 + d)
            : ((size_t)((b * 16 + h) * 64 + d) * 2048 + s);
          ((__bf16*)outp)[idx] = f2bf(val);
        }
      }
    }
  }
}

// ---------------------------------------------------------------------------
// Causal flash attention — REVERTED to the proven split-KV LDS-staged kernel
// (round 7/8/9), with STRIP-MERGE: block y's two strips (qb=15-y heavy,
// qb=y light) have nested causal ranges, so one KV sweep serves both.
// Stage each pair ONCE (np_h=16-y pairs vs 17 before), compute heavy-strip
// work and (while in range) light-strip work against the same staged tiles.
// Staging traffic -26%, barriers -25%; MFMA/softmax work unchanged.
// LDS (64KB) caps occupancy at 2 blocks/CU, so the extra VGPRs for the
// second strip state are free. 32x32x16 MFMA, swapped-operand, P in regs,
// FIXED-MAX softmax (p = exp2((s-40)*CE); split-KV partials purely additive).
// ---------------------------------------------------------------------------
__global__ __launch_bounds__(512, 3) void attn_fwd(
    const __bf16* __restrict__ Qh, const __bf16* __restrict__ Kh,
    const __bf16* __restrict__ Vt, __bf16* __restrict__ Ctx)
{
  __shared__ __bf16 KVs[8][64 * 64];                 // 64 KB

  const int tid = threadIdx.x;
  const int lane = tid & 63;
  const int l31 = lane & 31, hl = lane >> 5;
  const int w = tid >> 6;                            // 0..7
  const int wq3 = w & 3, p = w >> 2;                 // q-strip quarter, kv parity
  const int bh = blockIdx.x;
  const int b = bh >> 4, h = bh & 15;
  const int y = blockIdx.y;
  const float CE = 0.18033688f;                      // (1/sqrt(64)) * log2(e)
  const float MC = 40.0f * CE;                       // fixed softmax max (raw units)

  const int qbh = 15 - y, qbl = y;                   // heavy / light strips
  const int qwh = qbh * 128 + wq3 * 32, qwl = qbl * 128 + wq3 * 32;
  const int qgh = qwh + l31, qgl = qwl + l31;
  const int nph = qbh + 1, npl = qbl + 1;            // pair-steps (npl <= nph)

  // stage KV tile pair (2tp, 2tp+1) into slots {2*(tp&1), 2*(tp&1)+1}
  auto stagePair = [&](int tp) {
    const int base = 2 * (tp & 1);
    const int c = tid;                               // 512 chunks of 16B per tile
    const int r = c >> 3, sl = c & 7;
    const int so = 8 * (sl ^ (r & 7));               // inverse-swizzled source offset
#pragma unroll
    for (int i = 0; i < 2; ++i) {
      const int kv0 = (2 * tp + i) * 64, s = base + i;
      load_lds16(&Kh[((size_t)bh * 2048 + kv0 + r) * 64 + so], &KVs[s][c * 8]);
      load_lds16(&Vt[((size_t)bh * 64 + r) * 2048 + kv0 + so], &KVs[4 + s][c * 8]);
    }
  };

  // Q fragments (B-operand): B[k=d][n=q=l31], d = ds*16 + hl*8 + j
  bf16x8 qFh[4], qFl[4];
#pragma unroll
  for (int ds = 0; ds < 4; ++ds) {
    qFh[ds] = *(const bf16x8*)&Qh[((size_t)bh * 2048 + qgh) * 64 + ds * 16 + hl * 8];
    qFl[ds] = *(const bf16x8*)&Qh[((size_t)bh * 2048 + qgl) * 64 + ds * 16 + hl * 8];
  }

  f32x16 oTh[2] = {}, oTl[2] = {};   // O^T: d = dblk*32 + (r&3)+8*(r>>2)+4*hl, q=l31
  float lrunh = 0.f, lrunl = 0.f;

  // one KV tile (64 rows) for one strip: S^T -> mask -> exp -> P frags -> PV
  auto tileStep = [&](const __bf16* ksm, const __bf16* vsm, int kv0, int qg,
                      int qw, bf16x8 (&qF)[4], f32x16 (&oT)[2], float& lrun) {
    f32x16 sT[2] = {};
#pragma unroll
    for (int kblk = 0; kblk < 2; ++kblk) {
      bf16x8 aK[4];
      const int r = kblk * 32 + l31;
#pragma unroll
      for (int ds = 0; ds < 4; ++ds)
        aK[ds] = *(const bf16x8*)&ksm[r * 64 + ((ds * 16 + hl * 8) ^ ((r & 7) * 8))];
      __builtin_amdgcn_s_setprio(1);
#pragma unroll
      for (int ds = 0; ds < 4; ++ds)
        sT[kblk] = __builtin_amdgcn_mfma_f32_32x32x16_bf16(aK[ds], qF[ds], sT[kblk], 0, 0, 0);
      __builtin_amdgcn_s_setprio(0);
    }

    if (kv0 + 63 > qw) {                             // diagonal tiles only
#pragma unroll
      for (int kblk = 0; kblk < 2; ++kblk)
#pragma unroll
        for (int r = 0; r < 16; ++r) {
          int kvg = kv0 + kblk * 32 + (r & 3) + 8 * (r >> 2) + 4 * hl;
          sT[kblk][r] = (kvg <= qg) ? sT[kblk][r] : -3e38f;
        }
    }

    unsigned c0[8], c1[8];
    float ps0 = 0.f, ps1 = 0.f, ps2 = 0.f, ps3 = 0.f;
#pragma unroll
    for (int w2 = 0; w2 < 8; ++w2) {
      float p0 = exp2f(__builtin_fmaf(sT[0][2 * w2],     CE, -MC));
      float p1 = exp2f(__builtin_fmaf(sT[0][2 * w2 + 1], CE, -MC));
      float p2 = exp2f(__builtin_fmaf(sT[1][2 * w2],     CE, -MC));
      float p3 = exp2f(__builtin_fmaf(sT[1][2 * w2 + 1], CE, -MC));
      ps0 += p0; ps1 += p1; ps2 += p2; ps3 += p3;
      c0[w2] = cvt_pk_bf16(p0, p1);
      c1[w2] = cvt_pk_bf16(p2, p3);
    }
    lrun += (ps0 + ps1) + (ps2 + ps3);

    uint32x4 Wv[4];
#pragma unroll
    for (int kblk = 0; kblk < 2; ++kblk)
#pragma unroll
      for (int ksl = 0; ksl < 2; ++ksl)
#pragma unroll
        for (int al = 0; al < 2; ++al) {
          unsigned cp = kblk ? c1[4 * ksl + al]     : c0[4 * ksl + al];
          unsigned cq = kblk ? c1[4 * ksl + 2 + al] : c0[4 * ksl + 2 + al];
          unsigned cqx = __shfl_xor(cq, 32);
          unsigned cpx = __shfl_xor(cp, 32);
          Wv[kblk * 2 + ksl][al]     = hl ? cqx : cp;
          Wv[kblk * 2 + ksl][al + 2] = hl ? cq  : cpx;
        }

#pragma unroll
    for (int dblk = 0; dblk < 2; ++dblk) {
      bf16x8 aV[4];
      const int r = dblk * 32 + l31;
#pragma unroll
      for (int ks = 0; ks < 4; ++ks)
        aV[ks] = *(const bf16x8*)&vsm[r * 64 + ((ks * 16 + hl * 8) ^ ((r & 7) * 8))];
      __builtin_amdgcn_s_setprio(1);
#pragma unroll
      for (int ks = 0; ks < 4; ++ks)
        oT[dblk] = __builtin_amdgcn_mfma_f32_32x32x16_bf16(
            aV[ks], __builtin_bit_cast(bf16x8, Wv[ks]), oT[dblk], 0, 0, 0);
      __builtin_amdgcn_s_setprio(0);
    }
  };

  // ---- merged KV sweep: stage once, serve both strips ----
  stagePair(0);
#pragma unroll 1
  for (int tp = 0; tp < nph; ++tp) {
    __syncthreads();                                 // pair tp staged; pair tp-1 done
    if (tp + 1 < nph) stagePair(tp + 1);             // cooperative: before any skip!
    const int kv0 = (2 * tp + p) * 64;               // this wave's tile (its parity)
    const __bf16* ksm = KVs[2 * (tp & 1) + p];
    const __bf16* vsm = KVs[4 + 2 * (tp & 1) + p];
    if (kv0 <= qwh + 31)
      tileStep(ksm, vsm, kv0, qgh, qwh, qFh, oTh, lrunh);
    if (tp < npl && kv0 <= qwl + 31)
      tileStep(ksm, vsm, kv0, qgl, qwl, qFl, oTl, lrunl);
  }

  // ---- combine parity partials (fixed max -> pure sums), heavy then light ----
  float* ex = (float*)KVs + wq3 * 2176 + lane * 34;
  auto combine = [&](f32x16 (&oT)[2], float lrun, int qg) {
    __syncthreads();                                 // LDS free / prev phase done
    if (p == 1) {
      lrun += __shfl_xor(lrun, 32);
#pragma unroll
      for (int dblk = 0; dblk < 2; ++dblk)
#pragma unroll
        for (int rb = 0; rb < 8; ++rb)
          *(float2*)(ex + dblk * 16 + rb * 2) =
              make_float2(oT[dblk][2 * rb], oT[dblk][2 * rb + 1]);
      ex[32] = lrun;
    }
    __syncthreads();
    if (p == 0) {
      lrun += __shfl_xor(lrun, 32);
      lrun += ex[32];
#pragma unroll
      for (int dblk = 0; dblk < 2; ++dblk)
#pragma unroll
        for (int rb = 0; rb < 8; ++rb) {
          float2 v = *(float2*)(ex + dblk * 16 + rb * 2);
          oT[dblk][2 * rb]     += v.x;
          oT[dblk][2 * rb + 1] += v.y;
        }
      const float inv = 1.0f / fmaxf(lrun, 1e-30f);
#pragma unroll
      for (int dblk = 0; dblk < 2; ++dblk)
#pragma unroll
        for (int rb = 0; rb < 4; ++rb) {
          unsigned u0 = cvt_pk_bf16(oT[dblk][4 * rb]     * inv, oT[dblk][4 * rb + 1] * inv);
          unsigned u1 = cvt_pk_bf16(oT[dblk][4 * rb + 2] * inv, oT[dblk][4 * rb + 3] * inv);
          int d = dblk * 32 + rb * 8 + 4 * hl;
          size_t idx = ((size_t)(b * 2048 + qg)) * 1024 + h * 64 + d;
          *(uint2*)&Ctx[idx] = make_uint2(u0, u1);
        }
    }
  };
  combine(oTh, lrunh, qgh);
  combine(oTl, lrunl, qgl);
}

// ---------------------------------------------------------------------------
extern "C" void kernel_launch(void* const* d_in, const int* in_sizes, int n_in,
                              void* d_out, int out_size, void* d_ws, size_t ws_size,
                              hipStream_t stream) {
  const float* q  = (const float*)d_in[0];
  const float* k  = (const float*)d_in[1];
  const float* v  = (const float*)d_in[2];
  const float* wq = (const float*)d_in[3];
  const float* bq = (const float*)d_in[4];
  const float* wk = (const float*)d_in[5];
  const float* bk = (const float*)d_in[6];
  const float* wv = (const float*)d_in[7];
  const float* bv = (const float*)d_in[8];
  const float* wo = (const float*)d_in[9];
  const float* bo = (const float*)d_in[10];
  float* out = (float*)d_out;
  char* ws = (char*)d_ws;

  const size_t MB = 1024 * 1024;
  __bf16* Wqb  = (__bf16*)(ws + 0 * MB);
  __bf16* Wkb  = (__bf16*)(ws + 2 * MB);
  __bf16* Wvb  = (__bf16*)(ws + 4 * MB);
  __bf16* Wob  = (__bf16*)(ws + 6 * MB);
  __bf16* Ctx  = (__bf16*)(ws + 8 * MB);   // 16 MB
  __bf16* Qh   = (__bf16*)(ws + 24 * MB);
  __bf16* Kh   = (__bf16*)(ws + 40 * MB);
  __bf16* Vt   = (__bf16*)(ws + 56 * MB);  // ends at 72 MB

  const int W8 = 1024 * 1024 / 8;

  convert_w4<<<2048, 256, 0, stream>>>(wq, wk, wv, wo, Wqb, Wkb, Wvb, Wob, W8);

  gemm_qkv<<<dim3(64, 8, 3), 256, 0, stream>>>(q, k, v, Wqb, Wkb, Wvb,
                                               bq, bk, bv, Qh, Kh, Vt);

  attn_fwd<<<dim3(64, 8), 512, 0, stream>>>(Qh, Kh, Vt, Ctx);

  gemm_bt<2><<<dim3(64, 8), 256, 0, stream>>>(Ctx, Wob, bo, out);
}

// Round 12
// 217.832 us; speedup vs baseline: 1.6938x; 1.0054x over previous
//
#include <hip/hip_runtime.h>

#define DEVI __device__ __forceinline__

typedef __attribute__((ext_vector_type(8))) __bf16 bf16x8;
typedef __attribute__((ext_vector_type(4))) float f32x4;
typedef __attribute__((ext_vector_type(16))) float f32x16;
typedef __attribute__((ext_vector_type(4))) unsigned uint32x4;

DEVI __bf16 f2bf(float f) {
  unsigned u = __builtin_bit_cast(unsigned, f);
  unsigned r = u + 0x7fffu + ((u >> 16) & 1u);
  unsigned short h = (unsigned short)(r >> 16);
  return __builtin_bit_cast(__bf16, h);
}

DEVI unsigned cvt_pk_bf16(float lo, float hi) {
  unsigned r;
  asm("v_cvt_pk_bf16_f32 %0, %1, %2" : "=v"(r) : "v"(lo), "v"(hi));
  return r;
}

DEVI void load_lds16(const void* g, void* l) {
  __builtin_amdgcn_global_load_lds((__attribute__((address_space(1))) const void*)g,
                                   (__attribute__((address_space(3))) void*)l,
                                   16, 0, 0);
}

// ---------------------------------------------------------------------------
// fp32 -> bf16 conversion, 8 elems/thread
// ---------------------------------------------------------------------------
__global__ void convert_bf16(const float* __restrict__ in, __bf16* __restrict__ out, int n8) {
  int stride = gridDim.x * blockDim.x;
  for (int i = blockIdx.x * blockDim.x + threadIdx.x; i < n8; i += stride) {
    float4 a = ((const float4*)in)[i * 2];
    float4 b = ((const float4*)in)[i * 2 + 1];
    bf16x8 o;
    o[0] = f2bf(a.x); o[1] = f2bf(a.y); o[2] = f2bf(a.z); o[3] = f2bf(a.w);
    o[4] = f2bf(b.x); o[5] = f2bf(b.y); o[6] = f2bf(b.z); o[7] = f2bf(b.w);
    ((bf16x8*)out)[i] = o;
  }
}

// all four 1024x1024 weight matrices in one launch
__global__ void convert_w4(const float* __restrict__ w0, const float* __restrict__ w1,
                           const float* __restrict__ w2, const float* __restrict__ w3,
                           __bf16* __restrict__ o0, __bf16* __restrict__ o1,
                           __bf16* __restrict__ o2, __bf16* __restrict__ o3, int n8) {
  int stride = gridDim.x * blockDim.x;
  for (int i = blockIdx.x * blockDim.x + threadIdx.x; i < 4 * n8; i += stride) {
    int sel = i / n8, j = i - sel * n8;
    const float* in = sel == 0 ? w0 : sel == 1 ? w1 : sel == 2 ? w2 : w3;
    __bf16* out = sel == 0 ? o0 : sel == 1 ? o1 : sel == 2 ? o2 : o3;
    float4 a = ((const float4*)in)[j * 2];
    float4 b = ((const float4*)in)[j * 2 + 1];
    bf16x8 o;
    o[0] = f2bf(a.x); o[1] = f2bf(a.y); o[2] = f2bf(a.z); o[3] = f2bf(a.w);
    o[4] = f2bf(b.x); o[5] = f2bf(b.y); o[6] = f2bf(b.z); o[7] = f2bf(b.w);
    ((bf16x8*)out)[j] = o;
  }
}

// ---------------------------------------------------------------------------
// gemm_big: out[m,n] = A[m,:] . W[n,:] + bias[n]  (A bf16 [8192][1024], B^T).
// 256x128 tile, BK=32, 8 waves (4 row x 2 col, each 64x64 out).
// Scaled clone of the verified 128² depth-2 kernel: triple-buffered 72KB LDS,
// stage(kt+2) each step, s_waitcnt vmcnt(3) + s_barrier (retires stage(kt),
// issued 2 steps ~1200cy earlier -> no stall; 3 gloads/thread/step FIFO).
// Same (r>>1)&3 16B-slot XOR swizzle both sides. Grid (32,8) = 256 blocks =
// exactly 1/CU, no tail; id%8 = bx%8 -> same-bx blocks share A-panel per XCD.
// SEL 0: bf16 [BH][S][64] (Qh) | 1: same (Kh) | 2: bf16 [BH][64][S] (Vt)
// SEL 3: fp32 [M][1024] (final output)
// ---------------------------------------------------------------------------
template<int SEL>
__global__ __launch_bounds__(512, 2) void gemm_big(
    const __bf16* __restrict__ A, const __bf16* __restrict__ W,
    const float* __restrict__ bias, void* __restrict__ outp)
{
  __shared__ __bf16 As[3][256 * 32];                 // 3 x 16KB
  __shared__ __bf16 Bs[3][128 * 32];                 // 3 x 8KB
  const int tid = threadIdx.x;
  const int lane = tid & 63;
  const int ln = lane & 15, g = lane >> 4;
  const int w = tid >> 6;                            // 0..7
  const int wr = w >> 1, wc = w & 1;                 // 4 x 2 wave grid
  const int row0 = blockIdx.x * 256, col0 = blockIdx.y * 128;

  f32x4 acc[4][4] = {};

  auto stage = [&](int buf, int kt) {
    const int k0 = kt * 32;
#pragma unroll
    for (int i = 0; i < 2; ++i) {                    // A: 1024 chunks of 16B
      int c = tid + 512 * i;
      int r = c >> 2, sl = c & 3;
      int so = 8 * (sl ^ ((r >> 1) & 3));            // inverse-swizzled source
      load_lds16(&A[(size_t)(row0 + r) * 1024 + k0 + so], &As[buf][c * 8]);
    }
    {                                                // B: 512 chunks
      int c = tid;
      int r = c >> 2, sl = c & 3;
      int so = 8 * (sl ^ ((r >> 1) & 3));
      load_lds16(&W[(size_t)(col0 + r) * 1024 + k0 + so], &Bs[buf][c * 8]);
    }
  };

  auto compute = [&](int buf) {
    const __bf16* as = As[buf];
    const __bf16* bs = Bs[buf];
    bf16x8 aF[4], bF[4];
#pragma unroll
    for (int mi = 0; mi < 4; ++mi) {
      int r = wr * 64 + mi * 16 + ln;                // 0..255
      aF[mi] = *(const bf16x8*)&as[r * 32 + ((g * 8) ^ (((r >> 1) & 3) * 8))];
    }
#pragma unroll
    for (int ni = 0; ni < 4; ++ni) {
      int r = wc * 64 + ni * 16 + ln;                // 0..127
      bF[ni] = *(const bf16x8*)&bs[r * 32 + ((g * 8) ^ (((r >> 1) & 3) * 8))];
    }
    __builtin_amdgcn_s_setprio(1);
#pragma unroll
    for (int mi = 0; mi < 4; ++mi)
#pragma unroll
      for (int ni = 0; ni < 4; ++ni)
        acc[mi][ni] = __builtin_amdgcn_mfma_f32_16x16x32_bf16(aF[mi], bF[ni], acc[mi][ni], 0, 0, 0);
    __builtin_amdgcn_s_setprio(0);
  };

#define GB_STEP(KT, B) \
  asm volatile("s_waitcnt vmcnt(3)" ::: "memory"); \
  __builtin_amdgcn_s_barrier(); \
  asm volatile("" ::: "memory"); \
  stage(((B) + 2) % 3, (KT) + 2); \
  compute(B);

  stage(0, 0);                                       // 3 in flight
  stage(1, 1);                                       // 6 in flight
#pragma unroll 1
  for (int u = 0; u < 10; ++u) {                     // kt = 0..29
    const int kt = 3 * u;
    GB_STEP(kt + 0, 0)
    GB_STEP(kt + 1, 1)
    GB_STEP(kt + 2, 2)
  }
  // kt=30: retire S30 (issued kt=28); S31 stays in flight
  asm volatile("s_waitcnt vmcnt(3)" ::: "memory");
  __builtin_amdgcn_s_barrier();
  asm volatile("" ::: "memory");
  compute(0);
  // kt=31: drain
  asm volatile("s_waitcnt vmcnt(0)" ::: "memory");
  __builtin_amdgcn_s_barrier();
  asm volatile("" ::: "memory");
  compute(1);
#undef GB_STEP

#pragma unroll
  for (int ni = 0; ni < 4; ++ni) {
    int n = col0 + wc * 64 + ni * 16 + ln;
    float bv = bias[n];
#pragma unroll
    for (int mi = 0; mi < 4; ++mi) {
#pragma unroll
      for (int i = 0; i < 4; ++i) {
        int m = row0 + wr * 64 + mi * 16 + g * 4 + i;   // C: row=(l>>4)*4+i, col=l&15
        float val = acc[mi][ni][i] + bv;
        if (SEL == 3) {
          ((float*)outp)[(size_t)m * 1024 + n] = val;
        } else {
          int b = m >> 11, s = m & 2047, h = n >> 6, d = n & 63;
          size_t idx = (SEL == 2)
            ? ((size_t)((b * 16 + h) * 64 + d) * 2048 + s)
            : ((size_t)((b * 16 + h) * 2048 + s) * 64 + d);
          ((__bf16*)outp)[idx] = f2bf(val);
        }
      }
    }
  }
}

// ---------------------------------------------------------------------------
// Causal flash attention (round-7 proven version, reverted): 32x32x16 MFMA,
// swapped-operand, P in registers, FIXED-MAX softmax, split-KV 8-wave blocks,
// work-balanced (strip 15-y then strip y).
// ---------------------------------------------------------------------------
__global__ __launch_bounds__(512, 4) void attn_fwd(
    const __bf16* __restrict__ Qh, const __bf16* __restrict__ Kh,
    const __bf16* __restrict__ Vt, __bf16* __restrict__ Ctx)
{
  __shared__ __bf16 KVs[8][64 * 64];                 // 64 KB

  const int tid = threadIdx.x;
  const int lane = tid & 63;
  const int l31 = lane & 31, hl = lane >> 5;
  const int w = tid >> 6;                            // 0..7
  const int wq3 = w & 3, p = w >> 2;                 // q-strip quarter, kv parity
  const int bh = blockIdx.x;
  const int b = bh >> 4, h = bh & 15;
  const float CE = 0.18033688f;                      // (1/sqrt(64)) * log2(e)
  const float MC = 40.0f * CE;                       // fixed softmax max (raw units)

  auto stagePair = [&](int tp) {
    const int base = 2 * (tp & 1);
    const int c = tid;
    const int r = c >> 3, sl = c & 7;
    const int so = 8 * (sl ^ (r & 7));
#pragma unroll
    for (int i = 0; i < 2; ++i) {
      const int kv0 = (2 * tp + i) * 64, s = base + i;
      load_lds16(&Kh[((size_t)bh * 2048 + kv0 + r) * 64 + so], &KVs[s][c * 8]);
      load_lds16(&Vt[((size_t)bh * 64 + r) * 2048 + kv0 + so], &KVs[4 + s][c * 8]);
    }
  };

  auto strip = [&](int qb) {
    const int q0 = qb * 128;
    const int qw = q0 + wq3 * 32;
    const int qglob = qw + l31;
    const int np = qb + 1;

    bf16x8 qF[4];
#pragma unroll
    for (int ds = 0; ds < 4; ++ds)
      qF[ds] = *(const bf16x8*)&Qh[((size_t)bh * 2048 + qglob) * 64 + ds * 16 + hl * 8];

    f32x16 oT[2] = {};
    float lrun = 0.f;

    __syncthreads();
    stagePair(0);
    for (int tp = 0; tp < np; ++tp) {
      __syncthreads();
      if (tp + 1 < np) stagePair(tp + 1);
      const int kv0 = (2 * tp + p) * 64;
      if (kv0 > qw + 31) continue;
      const __bf16* ksm = KVs[2 * (tp & 1) + p];
      const __bf16* vsm = KVs[4 + 2 * (tp & 1) + p];

      f32x16 sT[2] = {};
#pragma unroll
      for (int kblk = 0; kblk < 2; ++kblk) {
        bf16x8 aK[4];
        const int r = kblk * 32 + l31;
#pragma unroll
        for (int ds = 0; ds < 4; ++ds)
          aK[ds] = *(const bf16x8*)&ksm[r * 64 + ((ds * 16 + hl * 8) ^ ((r & 7) * 8))];
        __builtin_amdgcn_s_setprio(1);
#pragma unroll
        for (int ds = 0; ds < 4; ++ds)
          sT[kblk] = __builtin_amdgcn_mfma_f32_32x32x16_bf16(aK[ds], qF[ds], sT[kblk], 0, 0, 0);
        __builtin_amdgcn_s_setprio(0);
      }

      if (kv0 + 63 > qw) {
#pragma unroll
        for (int kblk = 0; kblk < 2; ++kblk)
#pragma unroll
          for (int r = 0; r < 16; ++r) {
            int kvg = kv0 + kblk * 32 + (r & 3) + 8 * (r >> 2) + 4 * hl;
            sT[kblk][r] = (kvg <= qglob) ? sT[kblk][r] : -3e38f;
          }
      }

      unsigned c0[8], c1[8];
      float ps0 = 0.f, ps1 = 0.f, ps2 = 0.f, ps3 = 0.f;
#pragma unroll
      for (int w2 = 0; w2 < 8; ++w2) {
        float p0 = exp2f(__builtin_fmaf(sT[0][2 * w2],     CE, -MC));
        float p1 = exp2f(__builtin_fmaf(sT[0][2 * w2 + 1], CE, -MC));
        float p2 = exp2f(__builtin_fmaf(sT[1][2 * w2],     CE, -MC));
        float p3 = exp2f(__builtin_fmaf(sT[1][2 * w2 + 1], CE, -MC));
        ps0 += p0; ps1 += p1; ps2 += p2; ps3 += p3;
        c0[w2] = cvt_pk_bf16(p0, p1);
        c1[w2] = cvt_pk_bf16(p2, p3);
      }
      lrun += (ps0 + ps1) + (ps2 + ps3);

      uint32x4 Wv[4];
#pragma unroll
      for (int kblk = 0; kblk < 2; ++kblk)
#pragma unroll
        for (int ksl = 0; ksl < 2; ++ksl)
#pragma unroll
          for (int al = 0; al < 2; ++al) {
            unsigned cp = kblk ? c1[4 * ksl + al]     : c0[4 * ksl + al];
            unsigned cq = kblk ? c1[4 * ksl + 2 + al] : c0[4 * ksl + 2 + al];
            unsigned cqx = __shfl_xor(cq, 32);
            unsigned cpx = __shfl_xor(cp, 32);
            Wv[kblk * 2 + ksl][al]     = hl ? cqx : cp;
            Wv[kblk * 2 + ksl][al + 2] = hl ? cq  : cpx;
          }

#pragma unroll
      for (int dblk = 0; dblk < 2; ++dblk) {
        bf16x8 aV[4];
        const int r = dblk * 32 + l31;
#pragma unroll
        for (int ks = 0; ks < 4; ++ks)
          aV[ks] = *(const bf16x8*)&vsm[r * 64 + ((ks * 16 + hl * 8) ^ ((r & 7) * 8))];
        __builtin_amdgcn_s_setprio(1);
#pragma unroll
        for (int ks = 0; ks < 4; ++ks)
          oT[dblk] = __builtin_amdgcn_mfma_f32_32x32x16_bf16(
              aV[ks], __builtin_bit_cast(bf16x8, Wv[ks]), oT[dblk], 0, 0, 0);
        __builtin_amdgcn_s_setprio(0);
      }
    }

    __syncthreads();
    float* ex = (float*)KVs + wq3 * 2176 + lane * 34;
    if (p == 1) {
      lrun += __shfl_xor(lrun, 32);
#pragma unroll
      for (int dblk = 0; dblk < 2; ++dblk)
#pragma unroll
        for (int rb = 0; rb < 8; ++rb)
          *(float2*)(ex + dblk * 16 + rb * 2) =
              make_float2(oT[dblk][2 * rb], oT[dblk][2 * rb + 1]);
      ex[32] = lrun;
    }
    __syncthreads();
    if (p == 0) {
      lrun += __shfl_xor(lrun, 32);
      lrun += ex[32];
#pragma unroll
      for (int dblk = 0; dblk < 2; ++dblk)
#pragma unroll
        for (int rb = 0; rb < 8; ++rb) {
          float2 v = *(float2*)(ex + dblk * 16 + rb * 2);
          oT[dblk][2 * rb]     += v.x;
          oT[dblk][2 * rb + 1] += v.y;
        }
      const float inv = 1.0f / fmaxf(lrun, 1e-30f);
#pragma unroll
      for (int dblk = 0; dblk < 2; ++dblk)
#pragma unroll
        for (int rb = 0; rb < 4; ++rb) {
          unsigned u0 = cvt_pk_bf16(oT[dblk][4 * rb]     * inv, oT[dblk][4 * rb + 1] * inv);
          unsigned u1 = cvt_pk_bf16(oT[dblk][4 * rb + 2] * inv, oT[dblk][4 * rb + 3] * inv);
          int d = dblk * 32 + rb * 8 + 4 * hl;
          size_t idx = ((size_t)(b * 2048 + qglob)) * 1024 + h * 64 + d;
          *(uint2*)&Ctx[idx] = make_uint2(u0, u1);
        }
    }
  };

  strip(15 - (int)blockIdx.y);
  strip((int)blockIdx.y);
}

// ---------------------------------------------------------------------------
extern "C" void kernel_launch(void* const* d_in, const int* in_sizes, int n_in,
                              void* d_out, int out_size, void* d_ws, size_t ws_size,
                              hipStream_t stream) {
  const float* q  = (const float*)d_in[0];
  const float* k  = (const float*)d_in[1];
  const float* v  = (const float*)d_in[2];
  const float* wq = (const float*)d_in[3];
  const float* bq = (const float*)d_in[4];
  const float* wk = (const float*)d_in[5];
  const float* bk = (const float*)d_in[6];
  const float* wv = (const float*)d_in[7];
  const float* bv = (const float*)d_in[8];
  const float* wo = (const float*)d_in[9];
  const float* bo = (const float*)d_in[10];
  float* out = (float*)d_out;
  char* ws = (char*)d_ws;

  const size_t MB = 1024 * 1024;
  __bf16* Wqb  = (__bf16*)(ws + 0 * MB);
  __bf16* Wkb  = (__bf16*)(ws + 2 * MB);
  __bf16* Wvb  = (__bf16*)(ws + 4 * MB);
  __bf16* Wob  = (__bf16*)(ws + 6 * MB);
  __bf16* Abuf = (__bf16*)(ws + 8 * MB);   // 16 MB, reused for q/k/v acts then Ctx
  __bf16* Qh   = (__bf16*)(ws + 24 * MB);
  __bf16* Kh   = (__bf16*)(ws + 40 * MB);
  __bf16* Vt   = (__bf16*)(ws + 56 * MB);  // ends at 72 MB
  __bf16* Ctx  = Abuf;

  const int W8 = 1024 * 1024 / 8;
  const int X8 = 8192 * 1024 / 8;
  auto cgrid = [](int n8) { int nb = (n8 + 255) / 256; return dim3((unsigned)(nb < 2048 ? nb : 2048)); };

  convert_w4<<<2048, 256, 0, stream>>>(wq, wk, wv, wo, Wqb, Wkb, Wvb, Wob, W8);

  dim3 ggrid(32, 8);
  convert_bf16<<<cgrid(X8), 256, 0, stream>>>(q, Abuf, X8);
  gemm_big<0><<<ggrid, 512, 0, stream>>>(Abuf, Wqb, bq, Qh);
  convert_bf16<<<cgrid(X8), 256, 0, stream>>>(k, Abuf, X8);
  gemm_big<1><<<ggrid, 512, 0, stream>>>(Abuf, Wkb, bk, Kh);
  convert_bf16<<<cgrid(X8), 256, 0, stream>>>(v, Abuf, X8);
  gemm_big<2><<<ggrid, 512, 0, stream>>>(Abuf, Wvb, bv, Vt);

  attn_fwd<<<dim3(64, 8), 512, 0, stream>>>(Qh, Kh, Vt, Ctx);

  gemm_big<3><<<ggrid, 512, 0, stream>>>(Ctx, Wob, bo, out);
}

// Round 13
// 212.856 us; speedup vs baseline: 1.7334x; 1.0234x over previous
//
#include <hip/hip_runtime.h>

#define DEVI __device__ __forceinline__

typedef __attribute__((ext_vector_type(8))) __bf16 bf16x8;
typedef __attribute__((ext_vector_type(4))) float f32x4;
typedef __attribute__((ext_vector_type(16))) float f32x16;
typedef __attribute__((ext_vector_type(4))) unsigned uint32x4;

DEVI __bf16 f2bf(float f) {
  unsigned u = __builtin_bit_cast(unsigned, f);
  unsigned r = u + 0x7fffu + ((u >> 16) & 1u);
  unsigned short h = (unsigned short)(r >> 16);
  return __builtin_bit_cast(__bf16, h);
}

DEVI unsigned cvt_pk_bf16(float lo, float hi) {
  unsigned r;
  asm("v_cvt_pk_bf16_f32 %0, %1, %2" : "=v"(r) : "v"(lo), "v"(hi));
  return r;
}

DEVI void load_lds16(const void* g, void* l) {
  __builtin_amdgcn_global_load_lds((__attribute__((address_space(1))) const void*)g,
                                   (__attribute__((address_space(3))) void*)l,
                                   16, 0, 0);
}

// all four 1024x1024 weight matrices in one launch
__global__ void convert_w4(const float* __restrict__ w0, const float* __restrict__ w1,
                           const float* __restrict__ w2, const float* __restrict__ w3,
                           __bf16* __restrict__ o0, __bf16* __restrict__ o1,
                           __bf16* __restrict__ o2, __bf16* __restrict__ o3, int n8) {
  int stride = gridDim.x * blockDim.x;
  for (int i = blockIdx.x * blockDim.x + threadIdx.x; i < 4 * n8; i += stride) {
    int sel = i / n8, j = i - sel * n8;
    const float* in = sel == 0 ? w0 : sel == 1 ? w1 : sel == 2 ? w2 : w3;
    __bf16* out = sel == 0 ? o0 : sel == 1 ? o1 : sel == 2 ? o2 : o3;
    float4 a = ((const float4*)in)[j * 2];
    float4 b = ((const float4*)in)[j * 2 + 1];
    bf16x8 o;
    o[0] = f2bf(a.x); o[1] = f2bf(a.y); o[2] = f2bf(a.z); o[3] = f2bf(a.w);
    o[4] = f2bf(b.x); o[5] = f2bf(b.y); o[6] = f2bf(b.z); o[7] = f2bf(b.w);
    ((bf16x8*)out)[j] = o;
  }
}

// ---------------------------------------------------------------------------
// FUSED QKV projection GEMM, fp32-A staged via global_load_lds (NO reg-stage,
// NO separate convert pass). A tile = fp32 [128][32] (16KB), 16B-slot XOR
// swizzle slot^=(r&7) both-sides (inverse-swizzled global source + swizzled
// ds_read_b128); fragments converted LDS->reg with 4 cvt_pk each.
// W bf16 via gload_lds, slot^=((r>>1)&3) (proven gemm_bt path).
// Depth-2 counted pipeline: 6 loads/thread/step FIFO -> vmcnt(6); no ds_writes.
// Triple buffer 72KB LDS, 2 blocks/CU. sel=blockIdx.z.
// SEL 0: Qh bf16 [BH][S][64], PRE-SCALED by CE (softmax scale folded in).
// SEL 1: Kh bf16 [BH][S][64].  SEL 2: Vt bf16 [BH][64][S].
// ---------------------------------------------------------------------------
__global__ __launch_bounds__(256, 2) void gemm_qkv(
    const float* __restrict__ qa, const float* __restrict__ ka, const float* __restrict__ va,
    const __bf16* __restrict__ Wq, const __bf16* __restrict__ Wk, const __bf16* __restrict__ Wv,
    const float* __restrict__ bq, const float* __restrict__ bk, const float* __restrict__ bv,
    __bf16* __restrict__ Qh, __bf16* __restrict__ Kh, __bf16* __restrict__ Vt)
{
  __shared__ __align__(16) float  As[3][128 * 32];   // 3 x 16KB fp32
  __shared__ __align__(16) __bf16 Bs[3][128 * 32];   // 3 x 8KB bf16
  const int sel = blockIdx.z;
  const float* A = sel == 0 ? qa : sel == 1 ? ka : va;
  const __bf16* W = sel == 0 ? Wq : sel == 1 ? Wk : Wv;
  const float* bias = sel == 0 ? bq : sel == 1 ? bk : bv;
  __bf16* outp = sel == 0 ? Qh : sel == 1 ? Kh : Vt;
  const bool vmode = (sel == 2);
  const float osc = (sel == 0) ? 0.18033688f : 1.0f; // CE = (1/8)*log2(e) into Q

  const int tid = threadIdx.x;
  const int lane = tid & 63;
  const int ln = lane & 15, g = lane >> 4;
  const int w = tid >> 6;
  const int wr = w >> 1, wc = w & 1;
  const int id = blockIdx.y * 64 + blockIdx.x;
  const int bx = 8 * (id & 7) + ((id >> 3) & 7);     // XCD swizzle
  const int by = id >> 6;
  const int row0 = bx * 128, col0 = by * 128;

  f32x4 acc[4][4] = {};

  auto stage = [&](int buf, int kt) {                // 6 gloads/thread
    const int k0 = kt * 32;
#pragma unroll
    for (int i = 0; i < 4; ++i) {                    // A: 1024 chunks of 16B
      int c = tid + 256 * i;
      int r = c >> 3, sl = c & 7;                    // 8 slots per fp32 row
      int so = 4 * (sl ^ (r & 7));                   // inverse-swizzled src (floats)
      load_lds16(&A[(size_t)(row0 + r) * 1024 + k0 + so], &As[buf][c * 4]);
    }
#pragma unroll
    for (int i = 0; i < 2; ++i) {                    // B: 512 chunks of 16B
      int c = tid + 256 * i;
      int r = c >> 2, sl = c & 3;
      int so = 8 * (sl ^ ((r >> 1) & 3));
      load_lds16(&W[(size_t)(col0 + r) * 1024 + k0 + so], &Bs[buf][c * 8]);
    }
  };

  auto compute = [&](int buf) {
    const float* as = As[buf];
    const __bf16* bs = Bs[buf];
    bf16x8 aF[4], bF[4];
#pragma unroll
    for (int mi = 0; mi < 4; ++mi) {                 // fp32 -> bf16 in-reg
      int r = wr * 64 + mi * 16 + ln;
      int x = r & 7;
      f32x4 f0 = *(const f32x4*)&as[r * 32 + 4 * ((2 * g) ^ x)];
      f32x4 f1 = *(const f32x4*)&as[r * 32 + 4 * ((2 * g + 1) ^ x)];
      uint32x4 o;
      o[0] = cvt_pk_bf16(f0[0], f0[1]);
      o[1] = cvt_pk_bf16(f0[2], f0[3]);
      o[2] = cvt_pk_bf16(f1[0], f1[1]);
      o[3] = cvt_pk_bf16(f1[2], f1[3]);
      aF[mi] = __builtin_bit_cast(bf16x8, o);
    }
#pragma unroll
    for (int ni = 0; ni < 4; ++ni) {
      int r = wc * 64 + ni * 16 + ln;
      bF[ni] = *(const bf16x8*)&bs[r * 32 + ((g * 8) ^ (((r >> 1) & 3) * 8))];
    }
    __builtin_amdgcn_s_setprio(1);
#pragma unroll
    for (int mi = 0; mi < 4; ++mi)
#pragma unroll
      for (int ni = 0; ni < 4; ++ni)
        acc[mi][ni] = __builtin_amdgcn_mfma_f32_16x16x32_bf16(aF[mi], bF[ni], acc[mi][ni], 0, 0, 0);
    __builtin_amdgcn_s_setprio(0);
  };

  stage(0, 0);                                       // 6 in flight
  stage(1, 1);                                       // 12 in flight
#pragma unroll 1
  for (int kt = 0; kt < 31; ++kt) {
    // outstanding = stage(kt) 6 + stage(kt+1) 6; retire oldest 6 only
    asm volatile("s_waitcnt vmcnt(6)" ::: "memory");
    __builtin_amdgcn_s_barrier();
    asm volatile("" ::: "memory");
    if (kt + 2 < 32) stage((kt + 2) % 3, kt + 2);
    compute(kt % 3);
  }
  asm volatile("s_waitcnt vmcnt(0)" ::: "memory");   // peeled last tile
  __builtin_amdgcn_s_barrier();
  asm volatile("" ::: "memory");
  compute(31 % 3);

#pragma unroll
  for (int ni = 0; ni < 4; ++ni) {
    int n = col0 + wc * 64 + ni * 16 + ln;
    float bv = bias[n];
#pragma unroll
    for (int mi = 0; mi < 4; ++mi) {
#pragma unroll
      for (int i = 0; i < 4; ++i) {
        int m = row0 + wr * 64 + mi * 16 + g * 4 + i;   // C: row=(l>>4)*4+i, col=l&15
        float val = (acc[mi][ni][i] + bv) * osc;
        int b = m >> 11, s = m & 2047, h = n >> 6, d = n & 63;
        size_t idx = vmode
          ? ((size_t)((b * 16 + h) * 64 + d) * 2048 + s)
          : ((size_t)((b * 16 + h) * 2048 + s) * 64 + d);
        outp[idx] = f2bf(val);
      }
    }
  }
}

// ---------------------------------------------------------------------------
// Output GEMM (bf16 A = Ctx): depth-2 counted-vmcnt, fp32 out (proven 20us).
// ---------------------------------------------------------------------------
__global__ __launch_bounds__(256, 2) void gemm_out(
    const __bf16* __restrict__ A, const __bf16* __restrict__ W,
    const float* __restrict__ bias, float* __restrict__ outp)
{
  __shared__ __bf16 As[3][128 * 32];
  __shared__ __bf16 Bs[3][128 * 32];
  const int tid = threadIdx.x;
  const int lane = tid & 63;
  const int ln = lane & 15, g = lane >> 4;
  const int w = tid >> 6;
  const int wr = w >> 1, wc = w & 1;
  const int id = blockIdx.y * 64 + blockIdx.x;
  const int bx = 8 * (id & 7) + ((id >> 3) & 7);
  const int by = id >> 6;
  const int row0 = bx * 128, col0 = by * 128;

  f32x4 acc[4][4] = {};

  auto stage = [&](int buf, int kt) {
    const int k0 = kt * 32;
#pragma unroll
    for (int i = 0; i < 2; ++i) {
      int c = tid + 256 * i;
      int r = c >> 2, sl = c & 3;
      int so = 8 * (sl ^ ((r >> 1) & 3));
      load_lds16(&A[(size_t)(row0 + r) * 1024 + k0 + so], &As[buf][c * 8]);
      load_lds16(&W[(size_t)(col0 + r) * 1024 + k0 + so], &Bs[buf][c * 8]);
    }
  };

  auto compute = [&](int buf) {
    const __bf16* as = As[buf];
    const __bf16* bs = Bs[buf];
    bf16x8 aF[4], bF[4];
#pragma unroll
    for (int mi = 0; mi < 4; ++mi) {
      int r = wr * 64 + mi * 16 + ln;
      aF[mi] = *(const bf16x8*)&as[r * 32 + ((g * 8) ^ (((r >> 1) & 3) * 8))];
    }
#pragma unroll
    for (int ni = 0; ni < 4; ++ni) {
      int r = wc * 64 + ni * 16 + ln;
      bF[ni] = *(const bf16x8*)&bs[r * 32 + ((g * 8) ^ (((r >> 1) & 3) * 8))];
    }
    __builtin_amdgcn_s_setprio(1);
#pragma unroll
    for (int mi = 0; mi < 4; ++mi)
#pragma unroll
      for (int ni = 0; ni < 4; ++ni)
        acc[mi][ni] = __builtin_amdgcn_mfma_f32_16x16x32_bf16(aF[mi], bF[ni], acc[mi][ni], 0, 0, 0);
    __builtin_amdgcn_s_setprio(0);
  };

  stage(0, 0);
  stage(1, 1);
#pragma unroll 1
  for (int kt = 0; kt < 31; ++kt) {
    asm volatile("s_waitcnt vmcnt(4)" ::: "memory");
    __builtin_amdgcn_s_barrier();
    asm volatile("" ::: "memory");
    if (kt + 2 < 32) stage((kt + 2) % 3, kt + 2);
    compute(kt % 3);
  }
  asm volatile("s_waitcnt vmcnt(0)" ::: "memory");
  __builtin_amdgcn_s_barrier();
  asm volatile("" ::: "memory");
  compute(31 % 3);

#pragma unroll
  for (int ni = 0; ni < 4; ++ni) {
    int n = col0 + wc * 64 + ni * 16 + ln;
    float bv = bias[n];
#pragma unroll
    for (int mi = 0; mi < 4; ++mi) {
#pragma unroll
      for (int i = 0; i < 4; ++i) {
        int m = row0 + wr * 64 + mi * 16 + g * 4 + i;
        outp[(size_t)m * 1024 + n] = acc[mi][ni][i] + bv;
      }
    }
  }
}

// ---------------------------------------------------------------------------
// Causal flash attention (proven 81us structure): 32x32x16 MFMA, swapped-
// operand, P in registers, split-KV 8-wave blocks, work-balanced strips.
// Softmax scale CE is PRE-FOLDED into Qh, and the fixed-max constant is
// dropped entirely (softmax is scale-invariant: all p scale by 2^-MC which
// cancels in O/l) -> p = exp2(s) straight off the MFMA, no pre-FMA.
// ---------------------------------------------------------------------------
__global__ __launch_bounds__(512, 4) void attn_fwd(
    const __bf16* __restrict__ Qh, const __bf16* __restrict__ Kh,
    const __bf16* __restrict__ Vt, __bf16* __restrict__ Ctx)
{
  __shared__ __bf16 KVs[8][64 * 64];                 // 64 KB

  const int tid = threadIdx.x;
  const int lane = tid & 63;
  const int l31 = lane & 31, hl = lane >> 5;
  const int w = tid >> 6;                            // 0..7
  const int wq3 = w & 3, p = w >> 2;                 // q-strip quarter, kv parity
  const int bh = blockIdx.x;
  const int b = bh >> 4, h = bh & 15;

  auto stagePair = [&](int tp) {
    const int base = 2 * (tp & 1);
    const int c = tid;
    const int r = c >> 3, sl = c & 7;
    const int so = 8 * (sl ^ (r & 7));
#pragma unroll
    for (int i = 0; i < 2; ++i) {
      const int kv0 = (2 * tp + i) * 64, s = base + i;
      load_lds16(&Kh[((size_t)bh * 2048 + kv0 + r) * 64 + so], &KVs[s][c * 8]);
      load_lds16(&Vt[((size_t)bh * 64 + r) * 2048 + kv0 + so], &KVs[4 + s][c * 8]);
    }
  };

  auto strip = [&](int qb) {
    const int q0 = qb * 128;
    const int qw = q0 + wq3 * 32;
    const int qglob = qw + l31;
    const int np = qb + 1;

    bf16x8 qF[4];
#pragma unroll
    for (int ds = 0; ds < 4; ++ds)
      qF[ds] = *(const bf16x8*)&Qh[((size_t)bh * 2048 + qglob) * 64 + ds * 16 + hl * 8];

    f32x16 oT[2] = {};
    float lrun = 0.f;

    __syncthreads();
    stagePair(0);
    for (int tp = 0; tp < np; ++tp) {
      __syncthreads();
      if (tp + 1 < np) stagePair(tp + 1);
      const int kv0 = (2 * tp + p) * 64;
      if (kv0 > qw + 31) continue;
      const __bf16* ksm = KVs[2 * (tp & 1) + p];
      const __bf16* vsm = KVs[4 + 2 * (tp & 1) + p];

      f32x16 sT[2] = {};
#pragma unroll
      for (int kblk = 0; kblk < 2; ++kblk) {
        bf16x8 aK[4];
        const int r = kblk * 32 + l31;
#pragma unroll
        for (int ds = 0; ds < 4; ++ds)
          aK[ds] = *(const bf16x8*)&ksm[r * 64 + ((ds * 16 + hl * 8) ^ ((r & 7) * 8))];
        __builtin_amdgcn_s_setprio(1);
#pragma unroll
        for (int ds = 0; ds < 4; ++ds)
          sT[kblk] = __builtin_amdgcn_mfma_f32_32x32x16_bf16(aK[ds], qF[ds], sT[kblk], 0, 0, 0);
        __builtin_amdgcn_s_setprio(0);
      }

      if (kv0 + 63 > qw) {
#pragma unroll
        for (int kblk = 0; kblk < 2; ++kblk)
#pragma unroll
          for (int r = 0; r < 16; ++r) {
            int kvg = kv0 + kblk * 32 + (r & 3) + 8 * (r >> 2) + 4 * hl;
            sT[kblk][r] = (kvg <= qglob) ? sT[kblk][r] : -3e38f;
          }
      }

      unsigned c0[8], c1[8];
      float ps0 = 0.f, ps1 = 0.f, ps2 = 0.f, ps3 = 0.f;
#pragma unroll
      for (int w2 = 0; w2 < 8; ++w2) {
        float p0 = exp2f(sT[0][2 * w2]);
        float p1 = exp2f(sT[0][2 * w2 + 1]);
        float p2 = exp2f(sT[1][2 * w2]);
        float p3 = exp2f(sT[1][2 * w2 + 1]);
        ps0 += p0; ps1 += p1; ps2 += p2; ps3 += p3;
        c0[w2] = cvt_pk_bf16(p0, p1);
        c1[w2] = cvt_pk_bf16(p2, p3);
      }
      lrun += (ps0 + ps1) + (ps2 + ps3);

      uint32x4 Wv[4];
#pragma unroll
      for (int kblk = 0; kblk < 2; ++kblk)
#pragma unroll
        for (int ksl = 0; ksl < 2; ++ksl)
#pragma unroll
          for (int al = 0; al < 2; ++al) {
            unsigned cp = kblk ? c1[4 * ksl + al]     : c0[4 * ksl + al];
            unsigned cq = kblk ? c1[4 * ksl + 2 + al] : c0[4 * ksl + 2 + al];
            unsigned cqx = __shfl_xor(cq, 32);
            unsigned cpx = __shfl_xor(cp, 32);
            Wv[kblk * 2 + ksl][al]     = hl ? cqx : cp;
            Wv[kblk * 2 + ksl][al + 2] = hl ? cq  : cpx;
          }

#pragma unroll
      for (int dblk = 0; dblk < 2; ++dblk) {
        bf16x8 aV[4];
        const int r = dblk * 32 + l31;
#pragma unroll
        for (int ks = 0; ks < 4; ++ks)
          aV[ks] = *(const bf16x8*)&vsm[r * 64 + ((ks * 16 + hl * 8) ^ ((r & 7) * 8))];
        __builtin_amdgcn_s_setprio(1);
#pragma unroll
        for (int ks = 0; ks < 4; ++ks)
          oT[dblk] = __builtin_amdgcn_mfma_f32_32x32x16_bf16(
              aV[ks], __builtin_bit_cast(bf16x8, Wv[ks]), oT[dblk], 0, 0, 0);
        __builtin_amdgcn_s_setprio(0);
      }
    }

    __syncthreads();
    float* ex = (float*)KVs + wq3 * 2176 + lane * 34;
    if (p == 1) {
      lrun += __shfl_xor(lrun, 32);
#pragma unroll
      for (int dblk = 0; dblk < 2; ++dblk)
#pragma unroll
        for (int rb = 0; rb < 8; ++rb)
          *(float2*)(ex + dblk * 16 + rb * 2) =
              make_float2(oT[dblk][2 * rb], oT[dblk][2 * rb + 1]);
      ex[32] = lrun;
    }
    __syncthreads();
    if (p == 0) {
      lrun += __shfl_xor(lrun, 32);
      lrun += ex[32];
#pragma unroll
      for (int dblk = 0; dblk < 2; ++dblk)
#pragma unroll
        for (int rb = 0; rb < 8; ++rb) {
          float2 v = *(float2*)(ex + dblk * 16 + rb * 2);
          oT[dblk][2 * rb]     += v.x;
          oT[dblk][2 * rb + 1] += v.y;
        }
      const float inv = 1.0f / fmaxf(lrun, 1e-30f);
#pragma unroll
      for (int dblk = 0; dblk < 2; ++dblk)
#pragma unroll
        for (int rb = 0; rb < 4; ++rb) {
          unsigned u0 = cvt_pk_bf16(oT[dblk][4 * rb]     * inv, oT[dblk][4 * rb + 1] * inv);
          unsigned u1 = cvt_pk_bf16(oT[dblk][4 * rb + 2] * inv, oT[dblk][4 * rb + 3] * inv);
          int d = dblk * 32 + rb * 8 + 4 * hl;
          size_t idx = ((size_t)(b * 2048 + qglob)) * 1024 + h * 64 + d;
          *(uint2*)&Ctx[idx] = make_uint2(u0, u1);
        }
    }
  };

  strip(15 - (int)blockIdx.y);
  strip((int)blockIdx.y);
}

// ---------------------------------------------------------------------------
extern "C" void kernel_launch(void* const* d_in, const int* in_sizes, int n_in,
                              void* d_out, int out_size, void* d_ws, size_t ws_size,
                              hipStream_t stream) {
  const float* q  = (const float*)d_in[0];
  const float* k  = (const float*)d_in[1];
  const float* v  = (const float*)d_in[2];
  const float* wq = (const float*)d_in[3];
  const float* bq = (const float*)d_in[4];
  const float* wk = (const float*)d_in[5];
  const float* bk = (const float*)d_in[6];
  const float* wv = (const float*)d_in[7];
  const float* bv = (const float*)d_in[8];
  const float* wo = (const float*)d_in[9];
  const float* bo = (const float*)d_in[10];
  float* out = (float*)d_out;
  char* ws = (char*)d_ws;

  const size_t MB = 1024 * 1024;
  __bf16* Wqb  = (__bf16*)(ws + 0 * MB);
  __bf16* Wkb  = (__bf16*)(ws + 2 * MB);
  __bf16* Wvb  = (__bf16*)(ws + 4 * MB);
  __bf16* Wob  = (__bf16*)(ws + 6 * MB);
  __bf16* Ctx  = (__bf16*)(ws + 8 * MB);   // 16 MB
  __bf16* Qh   = (__bf16*)(ws + 24 * MB);
  __bf16* Kh   = (__bf16*)(ws + 40 * MB);
  __bf16* Vt   = (__bf16*)(ws + 56 * MB);  // ends at 72 MB

  const int W8 = 1024 * 1024 / 8;

  convert_w4<<<2048, 256, 0, stream>>>(wq, wk, wv, wo, Wqb, Wkb, Wvb, Wob, W8);

  gemm_qkv<<<dim3(64, 8, 3), 256, 0, stream>>>(q, k, v, Wqb, Wkb, Wvb,
                                               bq, bk, bv, Qh, Kh, Vt);

  attn_fwd<<<dim3(64, 8), 512, 0, stream>>>(Qh, Kh, Vt, Ctx);

  gemm_out<<<dim3(64, 8), 256, 0, stream>>>(Ctx, Wob, bo, out);
}

// Round 14
// 202.754 us; speedup vs baseline: 1.8197x; 1.0498x over previous
//
#include <hip/hip_runtime.h>

#define DEVI __device__ __forceinline__

typedef __attribute__((ext_vector_type(8))) __bf16 bf16x8;
typedef __attribute__((ext_vector_type(4))) float f32x4;
typedef __attribute__((ext_vector_type(16))) float f32x16;
typedef __attribute__((ext_vector_type(4))) unsigned uint32x4;

DEVI __bf16 f2bf(float f) {
  unsigned u = __builtin_bit_cast(unsigned, f);
  unsigned r = u + 0x7fffu + ((u >> 16) & 1u);
  unsigned short h = (unsigned short)(r >> 16);
  return __builtin_bit_cast(__bf16, h);
}

DEVI unsigned cvt_pk_bf16(float lo, float hi) {
  unsigned r;
  asm("v_cvt_pk_bf16_f32 %0, %1, %2" : "=v"(r) : "v"(lo), "v"(hi));
  return r;
}

DEVI void load_lds16(const void* g, void* l) {
  __builtin_amdgcn_global_load_lds((__attribute__((address_space(1))) const void*)g,
                                   (__attribute__((address_space(3))) void*)l,
                                   16, 0, 0);
}

// all four 1024x1024 weight matrices in one launch
__global__ void convert_w4(const float* __restrict__ w0, const float* __restrict__ w1,
                           const float* __restrict__ w2, const float* __restrict__ w3,
                           __bf16* __restrict__ o0, __bf16* __restrict__ o1,
                           __bf16* __restrict__ o2, __bf16* __restrict__ o3, int n8) {
  int stride = gridDim.x * blockDim.x;
  for (int i = blockIdx.x * blockDim.x + threadIdx.x; i < 4 * n8; i += stride) {
    int sel = i / n8, j = i - sel * n8;
    const float* in = sel == 0 ? w0 : sel == 1 ? w1 : sel == 2 ? w2 : w3;
    __bf16* out = sel == 0 ? o0 : sel == 1 ? o1 : sel == 2 ? o2 : o3;
    float4 a = ((const float4*)in)[j * 2];
    float4 b = ((const float4*)in)[j * 2 + 1];
    bf16x8 o;
    o[0] = f2bf(a.x); o[1] = f2bf(a.y); o[2] = f2bf(a.z); o[3] = f2bf(a.w);
    o[4] = f2bf(b.x); o[5] = f2bf(b.y); o[6] = f2bf(b.z); o[7] = f2bf(b.w);
    ((bf16x8*)out)[j] = o;
  }
}

// ---------------------------------------------------------------------------
// FUSED QKV projection GEMM (round-8 proven structure, 204.5us config):
// A fp32 -> regs (T14 reg-staged: float4 loads issued right after the
// barrier, latency hides under compute) -> cvt_pk -> swizzled ds_write;
// W via global_load_lds. 32KB LDS double-buffer, 3 blocks/CU. 2-phase loop
// with __syncthreads as the W-publish fence.
// SEL 0: Qh bf16 [BH][S][64], PRE-SCALED by CE (softmax scale folded in —
//        verified in round 13). SEL 1: Kh. SEL 2: Vt bf16 [BH][64][S].
// ---------------------------------------------------------------------------
__global__ __launch_bounds__(256, 3) void gemm_qkv(
    const float* __restrict__ qa, const float* __restrict__ ka, const float* __restrict__ va,
    const __bf16* __restrict__ Wq, const __bf16* __restrict__ Wk, const __bf16* __restrict__ Wv,
    const float* __restrict__ bq, const float* __restrict__ bk, const float* __restrict__ bv,
    __bf16* __restrict__ Qh, __bf16* __restrict__ Kh, __bf16* __restrict__ Vt)
{
  __shared__ __align__(16) __bf16 As[2][128 * 32];
  __shared__ __align__(16) __bf16 Bs[2][128 * 32];
  const int sel = blockIdx.z;
  const float* A = sel == 0 ? qa : sel == 1 ? ka : va;
  const __bf16* W = sel == 0 ? Wq : sel == 1 ? Wk : Wv;
  const float* bias = sel == 0 ? bq : sel == 1 ? bk : bv;
  __bf16* outp = sel == 0 ? Qh : sel == 1 ? Kh : Vt;
  const bool vmode = (sel == 2);
  const float osc = (sel == 0) ? 0.18033688f : 1.0f; // CE = (1/8)*log2(e) into Q

  const int tid = threadIdx.x;
  const int lane = tid & 63;
  const int ln = lane & 15, g = lane >> 4;
  const int w = tid >> 6;
  const int wr = w >> 1, wc = w & 1;
  const int id = blockIdx.y * 64 + blockIdx.x;
  const int bx = 8 * (id & 7) + ((id >> 3) & 7);     // XCD swizzle
  const int by = id >> 6;
  const int row0 = bx * 128, col0 = by * 128;

  const int ar = tid >> 1, ah = tid & 1;   // A staging: row (0..127), half (16 floats)
  const int axr = (ar >> 1) & 3;           // row swizzle term

  f32x4 acc[4][4] = {};
  float4 fA[4];

  auto issueA = [&](int kt) {              // 64B fp32 per thread -> regs
    const float4* src = (const float4*)&A[(size_t)(row0 + ar) * 1024 + kt * 32 + ah * 16];
#pragma unroll
    for (int j = 0; j < 4; ++j) fA[j] = src[j];
  };
  auto issueW = [&](int buf, int kt) {     // 2x gload_lds per thread
#pragma unroll
    for (int i = 0; i < 2; ++i) {
      int c = tid + 256 * i;
      int r = c >> 2, sl = c & 3;
      int so = 8 * (sl ^ ((r >> 1) & 3));  // inverse-swizzled source slot
      load_lds16(&W[(size_t)(col0 + r) * 1024 + kt * 32 + so], &Bs[buf][c * 8]);
    }
  };
  auto writeA = [&](int buf) {             // cvt + swizzled ds_write_b128 x2
#pragma unroll
    for (int j = 0; j < 2; ++j) {
      uint32x4 o;
      o[0] = cvt_pk_bf16(fA[2 * j].x, fA[2 * j].y);
      o[1] = cvt_pk_bf16(fA[2 * j].z, fA[2 * j].w);
      o[2] = cvt_pk_bf16(fA[2 * j + 1].x, fA[2 * j + 1].y);
      o[3] = cvt_pk_bf16(fA[2 * j + 1].z, fA[2 * j + 1].w);
      int s = 2 * ah + j;                  // source 16B slot
      *(uint32x4*)&As[buf][ar * 32 + (s ^ axr) * 8] = o;   // LDS slot = s ^ x
    }
  };
  auto compute = [&](int buf) {
    const __bf16* as = As[buf];
    const __bf16* bs = Bs[buf];
    bf16x8 aF[4], bF[4];
#pragma unroll
    for (int mi = 0; mi < 4; ++mi) {
      int r = wr * 64 + mi * 16 + ln;
      aF[mi] = *(const bf16x8*)&as[r * 32 + ((g * 8) ^ (((r >> 1) & 3) * 8))];
    }
#pragma unroll
    for (int ni = 0; ni < 4; ++ni) {
      int r = wc * 64 + ni * 16 + ln;
      bF[ni] = *(const bf16x8*)&bs[r * 32 + ((g * 8) ^ (((r >> 1) & 3) * 8))];
    }
    __builtin_amdgcn_s_setprio(1);
#pragma unroll
    for (int mi = 0; mi < 4; ++mi)
#pragma unroll
      for (int ni = 0; ni < 4; ++ni)
        acc[mi][ni] = __builtin_amdgcn_mfma_f32_16x16x32_bf16(aF[mi], bF[ni], acc[mi][ni], 0, 0, 0);
    __builtin_amdgcn_s_setprio(0);
  };

  // prologue: stage tile 0
  issueA(0); issueW(0, 0);
  writeA(0);                               // compiler waits for fA loads
  __syncthreads();                         // drains W(0) gload_lds, publishes buf0
#pragma unroll 1
  for (int kt = 0; kt < 32; ++kt) {
    const int cur = kt & 1, nxt = cur ^ 1;
    if (kt + 1 < 32) { issueA(kt + 1); issueW(nxt, kt + 1); }   // latency under compute
    compute(cur);
    if (kt + 1 < 32) writeA(nxt);          // regs -> LDS (other buffer)
    __syncthreads();                       // drain + publish buf nxt
  }

#pragma unroll
  for (int ni = 0; ni < 4; ++ni) {
    int n = col0 + wc * 64 + ni * 16 + ln;
    float bv = bias[n];
#pragma unroll
    for (int mi = 0; mi < 4; ++mi) {
#pragma unroll
      for (int i = 0; i < 4; ++i) {
        int m = row0 + wr * 64 + mi * 16 + g * 4 + i;   // C-layout: row=(l>>4)*4+i, col=l&15
        float val = (acc[mi][ni][i] + bv) * osc;
        int b = m >> 11, s = m & 2047, h = n >> 6, d = n & 63;
        size_t idx = vmode
          ? ((size_t)((b * 16 + h) * 64 + d) * 2048 + s)
          : ((size_t)((b * 16 + h) * 2048 + s) * 64 + d);
        outp[idx] = f2bf(val);
      }
    }
  }
}

// ---------------------------------------------------------------------------
// Output GEMM (bf16 A = Ctx): depth-2 counted-vmcnt, fp32 out (proven 20us).
// ---------------------------------------------------------------------------
__global__ __launch_bounds__(256, 2) void gemm_out(
    const __bf16* __restrict__ A, const __bf16* __restrict__ W,
    const float* __restrict__ bias, float* __restrict__ outp)
{
  __shared__ __bf16 As[3][128 * 32];
  __shared__ __bf16 Bs[3][128 * 32];
  const int tid = threadIdx.x;
  const int lane = tid & 63;
  const int ln = lane & 15, g = lane >> 4;
  const int w = tid >> 6;
  const int wr = w >> 1, wc = w & 1;
  const int id = blockIdx.y * 64 + blockIdx.x;
  const int bx = 8 * (id & 7) + ((id >> 3) & 7);
  const int by = id >> 6;
  const int row0 = bx * 128, col0 = by * 128;

  f32x4 acc[4][4] = {};

  auto stage = [&](int buf, int kt) {
    const int k0 = kt * 32;
#pragma unroll
    for (int i = 0; i < 2; ++i) {
      int c = tid + 256 * i;
      int r = c >> 2, sl = c & 3;
      int so = 8 * (sl ^ ((r >> 1) & 3));
      load_lds16(&A[(size_t)(row0 + r) * 1024 + k0 + so], &As[buf][c * 8]);
      load_lds16(&W[(size_t)(col0 + r) * 1024 + k0 + so], &Bs[buf][c * 8]);
    }
  };

  auto compute = [&](int buf) {
    const __bf16* as = As[buf];
    const __bf16* bs = Bs[buf];
    bf16x8 aF[4], bF[4];
#pragma unroll
    for (int mi = 0; mi < 4; ++mi) {
      int r = wr * 64 + mi * 16 + ln;
      aF[mi] = *(const bf16x8*)&as[r * 32 + ((g * 8) ^ (((r >> 1) & 3) * 8))];
    }
#pragma unroll
    for (int ni = 0; ni < 4; ++ni) {
      int r = wc * 64 + ni * 16 + ln;
      bF[ni] = *(const bf16x8*)&bs[r * 32 + ((g * 8) ^ (((r >> 1) & 3) * 8))];
    }
    __builtin_amdgcn_s_setprio(1);
#pragma unroll
    for (int mi = 0; mi < 4; ++mi)
#pragma unroll
      for (int ni = 0; ni < 4; ++ni)
        acc[mi][ni] = __builtin_amdgcn_mfma_f32_16x16x32_bf16(aF[mi], bF[ni], acc[mi][ni], 0, 0, 0);
    __builtin_amdgcn_s_setprio(0);
  };

  stage(0, 0);
  stage(1, 1);
#pragma unroll 1
  for (int kt = 0; kt < 31; ++kt) {
    asm volatile("s_waitcnt vmcnt(4)" ::: "memory");
    __builtin_amdgcn_s_barrier();
    asm volatile("" ::: "memory");
    if (kt + 2 < 32) stage((kt + 2) % 3, kt + 2);
    compute(kt % 3);
  }
  asm volatile("s_waitcnt vmcnt(0)" ::: "memory");
  __builtin_amdgcn_s_barrier();
  asm volatile("" ::: "memory");
  compute(31 % 3);

#pragma unroll
  for (int ni = 0; ni < 4; ++ni) {
    int n = col0 + wc * 64 + ni * 16 + ln;
    float bv = bias[n];
#pragma unroll
    for (int mi = 0; mi < 4; ++mi) {
#pragma unroll
      for (int i = 0; i < 4; ++i) {
        int m = row0 + wr * 64 + mi * 16 + g * 4 + i;
        outp[(size_t)m * 1024 + n] = acc[mi][ni][i] + bv;
      }
    }
  }
}

// ---------------------------------------------------------------------------
// Causal flash attention (proven split-KV structure; round-13 math verified):
// 32x32x16 MFMA, swapped-operand, P in registers, exp2-direct softmax
// (CE pre-folded into Qh; fixed-max constant dropped — scale-invariant).
// NEW (T12): P-redistribution via v_permlane32_swap_b32 (cp/cq are DISTINCT
// registers — round-3's NaN was the aliased swap_half(v,v), not this block).
// Replaces 16 ds_bpermute + 16 cndmask per tile-step with 8 permlane.
// ---------------------------------------------------------------------------
__global__ __launch_bounds__(512, 4) void attn_fwd(
    const __bf16* __restrict__ Qh, const __bf16* __restrict__ Kh,
    const __bf16* __restrict__ Vt, __bf16* __restrict__ Ctx)
{
  __shared__ __bf16 KVs[8][64 * 64];                 // 64 KB

  const int tid = threadIdx.x;
  const int lane = tid & 63;
  const int l31 = lane & 31, hl = lane >> 5;
  const int w = tid >> 6;                            // 0..7
  const int wq3 = w & 3, p = w >> 2;                 // q-strip quarter, kv parity
  const int bh = blockIdx.x;
  const int b = bh >> 4, h = bh & 15;

  auto stagePair = [&](int tp) {
    const int base = 2 * (tp & 1);
    const int c = tid;
    const int r = c >> 3, sl = c & 7;
    const int so = 8 * (sl ^ (r & 7));
#pragma unroll
    for (int i = 0; i < 2; ++i) {
      const int kv0 = (2 * tp + i) * 64, s = base + i;
      load_lds16(&Kh[((size_t)bh * 2048 + kv0 + r) * 64 + so], &KVs[s][c * 8]);
      load_lds16(&Vt[((size_t)bh * 64 + r) * 2048 + kv0 + so], &KVs[4 + s][c * 8]);
    }
  };

  auto strip = [&](int qb) {
    const int q0 = qb * 128;
    const int qw = q0 + wq3 * 32;
    const int qglob = qw + l31;
    const int np = qb + 1;

    bf16x8 qF[4];
#pragma unroll
    for (int ds = 0; ds < 4; ++ds)
      qF[ds] = *(const bf16x8*)&Qh[((size_t)bh * 2048 + qglob) * 64 + ds * 16 + hl * 8];

    f32x16 oT[2] = {};
    float lrun = 0.f;

    __syncthreads();
    stagePair(0);
    for (int tp = 0; tp < np; ++tp) {
      __syncthreads();
      if (tp + 1 < np) stagePair(tp + 1);
      const int kv0 = (2 * tp + p) * 64;
      if (kv0 > qw + 31) continue;
      const __bf16* ksm = KVs[2 * (tp & 1) + p];
      const __bf16* vsm = KVs[4 + 2 * (tp & 1) + p];

      f32x16 sT[2] = {};
#pragma unroll
      for (int kblk = 0; kblk < 2; ++kblk) {
        bf16x8 aK[4];
        const int r = kblk * 32 + l31;
#pragma unroll
        for (int ds = 0; ds < 4; ++ds)
          aK[ds] = *(const bf16x8*)&ksm[r * 64 + ((ds * 16 + hl * 8) ^ ((r & 7) * 8))];
        __builtin_amdgcn_s_setprio(1);
#pragma unroll
        for (int ds = 0; ds < 4; ++ds)
          sT[kblk] = __builtin_amdgcn_mfma_f32_32x32x16_bf16(aK[ds], qF[ds], sT[kblk], 0, 0, 0);
        __builtin_amdgcn_s_setprio(0);
      }

      if (kv0 + 63 > qw) {
#pragma unroll
        for (int kblk = 0; kblk < 2; ++kblk)
#pragma unroll
          for (int r = 0; r < 16; ++r) {
            int kvg = kv0 + kblk * 32 + (r & 3) + 8 * (r >> 2) + 4 * hl;
            sT[kblk][r] = (kvg <= qglob) ? sT[kblk][r] : -3e38f;
          }
      }

      unsigned c0[8], c1[8];
      float ps0 = 0.f, ps1 = 0.f, ps2 = 0.f, ps3 = 0.f;
#pragma unroll
      for (int w2 = 0; w2 < 8; ++w2) {
        float p0 = exp2f(sT[0][2 * w2]);
        float p1 = exp2f(sT[0][2 * w2 + 1]);
        float p2 = exp2f(sT[1][2 * w2]);
        float p3 = exp2f(sT[1][2 * w2 + 1]);
        ps0 += p0; ps1 += p1; ps2 += p2; ps3 += p3;
        c0[w2] = cvt_pk_bf16(p0, p1);
        c1[w2] = cvt_pk_bf16(p2, p3);
      }
      lrun += (ps0 + ps1) + (ps2 + ps3);

      // ---- in-register P redistribution via permlane32_swap (T12) ----
      // Wv[ks=2*kblk+ksl][a]: kv pair ksl*16 + hl*8 + 2a (+kblk*32), col q=l31.
      // word[al]   wants lo=cp.lo, hi=cq.lo; word[al+2] wants lo=cp.hi, hi=cq.hi
      // = exactly the two outputs of v_permlane32_swap_b32 cp, cq (hi(cp)<->lo(cq)).
      uint32x4 Wv[4];
#pragma unroll
      for (int kblk = 0; kblk < 2; ++kblk)
#pragma unroll
        for (int ksl = 0; ksl < 2; ++ksl)
#pragma unroll
          for (int al = 0; al < 2; ++al) {
            unsigned cp = kblk ? c1[4 * ksl + al]     : c0[4 * ksl + al];
            unsigned cq = kblk ? c1[4 * ksl + 2 + al] : c0[4 * ksl + 2 + al];
            asm volatile("v_permlane32_swap_b32 %0, %1" : "+v"(cp), "+v"(cq));
            Wv[kblk * 2 + ksl][al]     = cp;
            Wv[kblk * 2 + ksl][al + 2] = cq;
          }

#pragma unroll
      for (int dblk = 0; dblk < 2; ++dblk) {
        bf16x8 aV[4];
        const int r = dblk * 32 + l31;
#pragma unroll
        for (int ks = 0; ks < 4; ++ks)
          aV[ks] = *(const bf16x8*)&vsm[r * 64 + ((ks * 16 + hl * 8) ^ ((r & 7) * 8))];
        __builtin_amdgcn_s_setprio(1);
#pragma unroll
        for (int ks = 0; ks < 4; ++ks)
          oT[dblk] = __builtin_amdgcn_mfma_f32_32x32x16_bf16(
              aV[ks], __builtin_bit_cast(bf16x8, Wv[ks]), oT[dblk], 0, 0, 0);
        __builtin_amdgcn_s_setprio(0);
      }
    }

    __syncthreads();
    float* ex = (float*)KVs + wq3 * 2176 + lane * 34;
    if (p == 1) {
      lrun += __shfl_xor(lrun, 32);
#pragma unroll
      for (int dblk = 0; dblk < 2; ++dblk)
#pragma unroll
        for (int rb = 0; rb < 8; ++rb)
          *(float2*)(ex + dblk * 16 + rb * 2) =
              make_float2(oT[dblk][2 * rb], oT[dblk][2 * rb + 1]);
      ex[32] = lrun;
    }
    __syncthreads();
    if (p == 0) {
      lrun += __shfl_xor(lrun, 32);
      lrun += ex[32];
#pragma unroll
      for (int dblk = 0; dblk < 2; ++dblk)
#pragma unroll
        for (int rb = 0; rb < 8; ++rb) {
          float2 v = *(float2*)(ex + dblk * 16 + rb * 2);
          oT[dblk][2 * rb]     += v.x;
          oT[dblk][2 * rb + 1] += v.y;
        }
      const float inv = 1.0f / fmaxf(lrun, 1e-30f);
#pragma unroll
      for (int dblk = 0; dblk < 2; ++dblk)
#pragma unroll
        for (int rb = 0; rb < 4; ++rb) {
          unsigned u0 = cvt_pk_bf16(oT[dblk][4 * rb]     * inv, oT[dblk][4 * rb + 1] * inv);
          unsigned u1 = cvt_pk_bf16(oT[dblk][4 * rb + 2] * inv, oT[dblk][4 * rb + 3] * inv);
          int d = dblk * 32 + rb * 8 + 4 * hl;
          size_t idx = ((size_t)(b * 2048 + qglob)) * 1024 + h * 64 + d;
          *(uint2*)&Ctx[idx] = make_uint2(u0, u1);
        }
    }
  };

  strip(15 - (int)blockIdx.y);
  strip((int)blockIdx.y);
}

// ---------------------------------------------------------------------------
extern "C" void kernel_launch(void* const* d_in, const int* in_sizes, int n_in,
                              void* d_out, int out_size, void* d_ws, size_t ws_size,
                              hipStream_t stream) {
  const float* q  = (const float*)d_in[0];
  const float* k  = (const float*)d_in[1];
  const float* v  = (const float*)d_in[2];
  const float* wq = (const float*)d_in[3];
  const float* bq = (const float*)d_in[4];
  const float* wk = (const float*)d_in[5];
  const float* bk = (const float*)d_in[6];
  const float* wv = (const float*)d_in[7];
  const float* bv = (const float*)d_in[8];
  const float* wo = (const float*)d_in[9];
  const float* bo = (const float*)d_in[10];
  float* out = (float*)d_out;
  char* ws = (char*)d_ws;

  const size_t MB = 1024 * 1024;
  __bf16* Wqb  = (__bf16*)(ws + 0 * MB);
  __bf16* Wkb  = (__bf16*)(ws + 2 * MB);
  __bf16* Wvb  = (__bf16*)(ws + 4 * MB);
  __bf16* Wob  = (__bf16*)(ws + 6 * MB);
  __bf16* Ctx  = (__bf16*)(ws + 8 * MB);   // 16 MB
  __bf16* Qh   = (__bf16*)(ws + 24 * MB);
  __bf16* Kh   = (__bf16*)(ws + 40 * MB);
  __bf16* Vt   = (__bf16*)(ws + 56 * MB);  // ends at 72 MB

  const int W8 = 1024 * 1024 / 8;

  convert_w4<<<2048, 256, 0, stream>>>(wq, wk, wv, wo, Wqb, Wkb, Wvb, Wob, W8);

  gemm_qkv<<<dim3(64, 8, 3), 256, 0, stream>>>(q, k, v, Wqb, Wkb, Wvb,
                                               bq, bk, bv, Qh, Kh, Vt);

  attn_fwd<<<dim3(64, 8), 512, 0, stream>>>(Qh, Kh, Vt, Ctx);

  gemm_out<<<dim3(64, 8), 256, 0, stream>>>(Ctx, Wob, bo, out);
}